// Round 7
// baseline (1075.160 us; speedup 1.0000x reference)
//
#include <hip/hip_runtime.h>

#define D 128

using short8 = __attribute__((ext_vector_type(8))) short;
using f32x4 = __attribute__((ext_vector_type(4))) float;

__device__ inline unsigned short f2bf(float f) {
  unsigned u = __float_as_uint(f);
  u += 0x7fffu + ((u >> 16) & 1u);  // RNE
  return (unsigned short)(u >> 16);
}

// swizzled byte offset within a [128 rows][128 bf16] LDS/W-image tile (G4 fix)
__device__ inline int swz(int r, int kbyte) {
  return ((r << 8) + kbyte) ^ ((r & 7) << 4);
}

// relu on two packed bf16
__device__ inline unsigned relu_pk(unsigned w) {
  if (w & 0x8000u) w &= 0xffff0000u;
  if (w & 0x80000000u) w &= 0x0000ffffu;
  return w;
}

// ---------------- CSR build ----------------

__global__ __launch_bounds__(256) void count_int_kernel(const int* __restrict__ dst,
                                                        int* __restrict__ cnt, int n) {
  int i = blockIdx.x * 256 + threadIdx.x;
  if (i < n) atomicAdd(&cnt[dst[i]], 1);
}

__global__ __launch_bounds__(256) void blocksum_kernel(const int* __restrict__ cnt,
                                                       int* __restrict__ bsums, int n) {
  __shared__ int sh[256];
  int i = blockIdx.x * 256 + threadIdx.x;
  sh[threadIdx.x] = (i < n) ? cnt[i] : 0;
  __syncthreads();
#pragma unroll
  for (int off = 128; off > 0; off >>= 1) {
    if (threadIdx.x < off) sh[threadIdx.x] += sh[threadIdx.x + off];
    __syncthreads();
  }
  if (threadIdx.x == 0) bsums[blockIdx.x] = sh[0];
}

__global__ __launch_bounds__(256) void scan_bsums_kernel(int* __restrict__ bsums, int nb) {
  __shared__ int sh[256];
  __shared__ int carry;
  if (threadIdx.x == 0) carry = 0;
  __syncthreads();
  for (int base = 0; base < nb; base += 256) {
    int i = base + threadIdx.x;
    int v = (i < nb) ? bsums[i] : 0;
    sh[threadIdx.x] = v;
    __syncthreads();
#pragma unroll
    for (int off = 1; off < 256; off <<= 1) {
      int t = (threadIdx.x >= off) ? sh[threadIdx.x - off] : 0;
      __syncthreads();
      sh[threadIdx.x] += t;
      __syncthreads();
    }
    int incl = sh[threadIdx.x];
    if (i < nb) bsums[i] = carry + incl - v;  // exclusive
    __syncthreads();
    if (threadIdx.x == 0) carry += sh[255];
    __syncthreads();
  }
}

__global__ __launch_bounds__(256) void scan_finalize_kernel(const int* __restrict__ cnt,
                                                            const int* __restrict__ bsums,
                                                            int* __restrict__ rowptr,
                                                            int n, int total) {
  __shared__ int sh[256];
  int i = blockIdx.x * 256 + threadIdx.x;
  int v = (i < n) ? cnt[i] : 0;
  sh[threadIdx.x] = v;
  __syncthreads();
#pragma unroll
  for (int off = 1; off < 256; off <<= 1) {
    int t = (threadIdx.x >= off) ? sh[threadIdx.x - off] : 0;
    __syncthreads();
    sh[threadIdx.x] += t;
    __syncthreads();
  }
  if (i < n) {
    rowptr[i] = bsums[blockIdx.x] + sh[threadIdx.x] - v;
    if (i == n - 1) rowptr[n] = total;
  }
}

__global__ __launch_bounds__(256) void fill_kernel(const int* __restrict__ src,
                                                   const int* __restrict__ dst,
                                                   int* __restrict__ cursor,
                                                   int* __restrict__ slots, int n) {
  int i = blockIdx.x * 256 + threadIdx.x;
  if (i < n) {
    int pos = atomicAdd(&cursor[dst[i]], 1);
    slots[pos] = src[i];
  }
}

// ---------------- weight prep: write pre-swizzled LDS image (5 bf16 matrices) ----------------
// image layout per matrix: [c][k] tile, XOR-swizzled; PERM additionally permutes k
// so that k-position p corresponds to original col (p&7)*16 + (p>>3) — matching the
// permuted intermediate-buffer layout consumed as X by layer 1.
// Wb order: [0]=Wrpd+Wrdd (drug lin_r), [1]=Wldd, [2]=Wldp, [3]=Wrdp, [4]=Wlpd

template<bool PERM>
__global__ __launch_bounds__(256) void prep_weights_kernel(
    const float* __restrict__ Wrpd, const float* __restrict__ Wrdd,
    const float* __restrict__ Wldd, const float* __restrict__ Wldp,
    const float* __restrict__ Wrdp, const float* __restrict__ Wlpd,
    const float* __restrict__ bpd, const float* __restrict__ bdd,
    unsigned short* __restrict__ Wb, float* __restrict__ bsum) {
  int g = blockIdx.x * 256 + threadIdx.x;  // ushort4 granule id, 5*4096 total
  if (g < 5 * 4096) {
    int mat = g >> 12, idx = g & 4095;
    int c = idx >> 5, k4 = (idx & 31) * 4;  // k4 = first k-position of granule
    const float* src0;
    const float* src1 = nullptr;
    switch (mat) {
      case 0: src0 = Wrpd; src1 = Wrdd; break;
      case 1: src0 = Wldd; break;
      case 2: src0 = Wldp; break;
      case 3: src0 = Wrdp; break;
      default: src0 = Wlpd; break;
    }
    unsigned short v[4];
#pragma unroll
    for (int j = 0; j < 4; ++j) {
      int kp = k4 + j;
      int kc = PERM ? ((kp & 7) * 16 + (kp >> 3)) : kp;
      float f = src0[c * D + kc];
      if (src1) f += src1[c * D + kc];
      v[j] = f2bf(f);
    }
    *reinterpret_cast<ushort4*>((char*)(Wb + mat * D * D) + swz(c, k4 * 2)) =
        make_ushort4(v[0], v[1], v[2], v[3]);
  }
  if (g < D) bsum[g] = bpd[g] + bdd[g];
}

// ---------------- fragment loader ----------------

template<typename XT, bool RELU>
__device__ inline short8 ld_frag(const XT* __restrict__ p, bool valid) {
  if constexpr (sizeof(XT) == 4) {  // f32
    float4 v0 = make_float4(0.f, 0.f, 0.f, 0.f), v1 = v0;
    if (valid) {
      v0 = *reinterpret_cast<const float4*>(p);
      v1 = *reinterpret_cast<const float4*>(p + 4);
    }
    if (RELU) {
      v0.x = fmaxf(v0.x, 0.f); v0.y = fmaxf(v0.y, 0.f);
      v0.z = fmaxf(v0.z, 0.f); v0.w = fmaxf(v0.w, 0.f);
      v1.x = fmaxf(v1.x, 0.f); v1.y = fmaxf(v1.y, 0.f);
      v1.z = fmaxf(v1.z, 0.f); v1.w = fmaxf(v1.w, 0.f);
    }
    short8 s;
    s[0] = (short)f2bf(v0.x); s[1] = (short)f2bf(v0.y);
    s[2] = (short)f2bf(v0.z); s[3] = (short)f2bf(v0.w);
    s[4] = (short)f2bf(v1.x); s[5] = (short)f2bf(v1.y);
    s[6] = (short)f2bf(v1.z); s[7] = (short)f2bf(v1.w);
    return s;
  } else {  // bf16
    uint4 u = make_uint4(0, 0, 0, 0);
    if (valid) u = *reinterpret_cast<const uint4*>(p);
    if (RELU) { u.x = relu_pk(u.x); u.y = relu_pk(u.y); u.z = relu_pk(u.z); u.w = relu_pk(u.w); }
    union { uint4 u; short8 s; } cv; cv.u = u;
    return cv.s;
  }
}

// ---------------- fused multi-head GEMM (8 waves, 256-row macro-tile) ----------------
// head0: +bias; OUT0_F32 -> f32 standard-layout (d_out), else bf16 permuted-packed.
// heads 1..: bf16 permuted-packed (pos = (col&15)*8 + col>>4 -> one uint4 store per (m,r)).
// X prefetch double-buffered in registers; heads split into passes {0,1},{2} to cap VGPR.
// NOTE: __launch_bounds__(512) with NO min-blocks arg — round 6 showed (512,2) is
// honored as min 2 blocks/CU => 128-VGPR cap => massive scratch spills (hbm 3.4x).

template<typename XT, bool RELU, int NH, bool OUT0_F32>
__global__ __launch_bounds__(512) void fused_gemm_kernel(
    const XT* __restrict__ X, const unsigned short* __restrict__ Wb,
    const float* __restrict__ bias0, void* __restrict__ out0,
    unsigned short* __restrict__ out1, unsigned short* __restrict__ out2,
    int nrows, int ntiles) {
  __shared__ short Wsh[NH * D * D];
  const int tid = threadIdx.x;

  // Wb is the pre-swizzled LDS image: linear uint4 copy
  for (int i = tid; i < NH * 2048; i += 512)
    reinterpret_cast<uint4*>(Wsh)[i] = reinterpret_cast<const uint4*>(Wb)[i];
  __syncthreads();

  const int wv = tid >> 6, lane = tid & 63;
  const int l15 = lane & 15, lg = lane >> 4;
  const int rbase = wv * 32;

  float bias_c[8];
#pragma unroll
  for (int n = 0; n < 8; ++n) bias_c[n] = bias0[n * 16 + l15];

  auto loadA = [&](short8 (&a)[2][4], int tile) {
    size_t row0 = (size_t)tile * 256;
    long rem = (long)nrows - (long)row0;
    int limit = (int)(rem < 256 ? rem : 256);
    bool v0 = (rbase + l15) < limit, v1 = (rbase + l15 + 16) < limit;
    const XT* b0 = X + (row0 + rbase + l15) * D;
    const XT* b1 = X + (row0 + rbase + l15 + 16) * D;
#pragma unroll
    for (int t = 0; t < 4; ++t) {
      int k0 = t * 32 + lg * 8;
      a[0][t] = ld_frag<XT, RELU>(b0 + k0, v0);
      a[1][t] = ld_frag<XT, RELU>(b1 + k0, v1);
    }
  };

  // packed bf16 store (permuted layout): acc n-frags are lane-contiguous positions
  auto store_bf16 = [&](f32x4 (&acc)[2][8], unsigned short* out, size_t row0,
                        int limit, bool addb) {
#pragma unroll
    for (int m = 0; m < 2; ++m)
#pragma unroll
      for (int r = 0; r < 4; ++r) {
        int lrow = rbase + m * 16 + lg * 4 + r;
        if (lrow < limit) {
          float f[8];
#pragma unroll
          for (int n = 0; n < 8; ++n) f[n] = acc[m][n][r] + (addb ? bias_c[n] : 0.f);
          uint4 u;
          u.x = (unsigned)f2bf(f[0]) | ((unsigned)f2bf(f[1]) << 16);
          u.y = (unsigned)f2bf(f[2]) | ((unsigned)f2bf(f[3]) << 16);
          u.z = (unsigned)f2bf(f[4]) | ((unsigned)f2bf(f[5]) << 16);
          u.w = (unsigned)f2bf(f[6]) | ((unsigned)f2bf(f[7]) << 16);
          *reinterpret_cast<uint4*>(out + (row0 + lrow) * D + l15 * 8) = u;
        }
      }
  };

  auto store_f32 = [&](f32x4 (&acc)[2][8], float* out, size_t row0, int limit) {
#pragma unroll
    for (int m = 0; m < 2; ++m)
#pragma unroll
      for (int n = 0; n < 8; ++n) {
        const int col = n * 16 + l15;
#pragma unroll
        for (int r = 0; r < 4; ++r) {
          int lrow = rbase + m * 16 + lg * 4 + r;
          if (lrow < limit) out[(row0 + lrow) * D + col] = acc[m][n][r] + bias_c[n];
        }
      }
  };

  auto do_tile = [&](short8 (&acur)[2][4], short8 (&anext)[2][4], int tile) {
    int ntile = tile + (int)gridDim.x;
    if (ntile < ntiles) loadA(anext, ntile);  // prefetch hides under MFMA passes

    size_t row0 = (size_t)tile * 256;
    long rem = (long)nrows - (long)row0;
    int limit = (int)(rem < 256 ? rem : 256);

    // ---- pass 1: heads 0..P1-1 ----
    constexpr int P1 = (NH >= 2) ? 2 : 1;
    {
      f32x4 acc[P1][2][8] = {};
#pragma unroll
      for (int t = 0; t < 4; ++t) {
        const int kb = t * 64 + lg * 16;
#pragma unroll
        for (int h = 0; h < P1; ++h) {
          const char* base = (const char*)(Wsh + h * D * D);
#pragma unroll
          for (int n = 0; n < 8; ++n) {
            short8 b = *reinterpret_cast<const short8*>(base + swz(n * 16 + l15, kb));
            acc[h][0][n] = __builtin_amdgcn_mfma_f32_16x16x32_bf16(acur[0][t], b, acc[h][0][n], 0, 0, 0);
            acc[h][1][n] = __builtin_amdgcn_mfma_f32_16x16x32_bf16(acur[1][t], b, acc[h][1][n], 0, 0, 0);
          }
        }
      }
      if (OUT0_F32) store_f32(acc[0], (float*)out0, row0, limit);
      else          store_bf16(acc[0], (unsigned short*)out0, row0, limit, true);
      if (P1 > 1)   store_bf16(acc[1], out1, row0, limit, false);
    }
    // ---- pass 2: head 2 ----
    if constexpr (NH == 3) {
      f32x4 acc2[2][8] = {};
#pragma unroll
      for (int t = 0; t < 4; ++t) {
        const int kb = t * 64 + lg * 16;
        const char* base = (const char*)(Wsh + 2 * D * D);
#pragma unroll
        for (int n = 0; n < 8; ++n) {
          short8 b = *reinterpret_cast<const short8*>(base + swz(n * 16 + l15, kb));
          acc2[0][n] = __builtin_amdgcn_mfma_f32_16x16x32_bf16(acur[0][t], b, acc2[0][n], 0, 0, 0);
          acc2[1][n] = __builtin_amdgcn_mfma_f32_16x16x32_bf16(acur[1][t], b, acc2[1][n], 0, 0, 0);
        }
      }
      store_bf16(acc2, out2, row0, limit, false);
    }
  };

  short8 aA[2][4], aB[2][4];
  int tile = blockIdx.x;
  if (tile >= ntiles) return;
  loadA(aA, tile);
  while (true) {
    do_tile(aA, aB, tile);
    tile += gridDim.x;
    if (tile >= ntiles) break;
    do_tile(aB, aA, tile);
    tile += gridDim.x;
    if (tile >= ntiles) break;
  }
}

// ---------------- gather (CSR, no atomics) ----------------
// 16 lanes per dst node; lane owns 16B (8 bf16 positions) of the permuted 256B row.
// MODE 1: acc is bf16 permuted (elementwise uint4 RMW).
// MODE 0: acc is f32 standard layout -> un-permute: position lane*8+i == col i*16+lane.

__device__ inline void addbf8(float* sum, uint4 v) {
  sum[0] += __uint_as_float(v.x << 16);
  sum[1] += __uint_as_float(v.x & 0xffff0000u);
  sum[2] += __uint_as_float(v.y << 16);
  sum[3] += __uint_as_float(v.y & 0xffff0000u);
  sum[4] += __uint_as_float(v.z << 16);
  sum[5] += __uint_as_float(v.z & 0xffff0000u);
  sum[6] += __uint_as_float(v.w << 16);
  sum[7] += __uint_as_float(v.w & 0xffff0000u);
}

__device__ inline float gather_one(const uint4* __restrict__ Y4,
                                   const int* __restrict__ rowptr,
                                   const int* __restrict__ slots,
                                   int node, int lane, float* sum) {
  int s0 = rowptr[node], s1 = rowptr[node + 1];
  for (int chunk = s0; chunk < s1; chunk += 16) {
    int idx = chunk + lane;
    int pre = (idx < s1) ? slots[idx] : 0;
    int m = s1 - chunk; if (m > 16) m = 16;
    int j = 0;
    for (; j + 4 <= m; j += 4) {
      int sA = __shfl(pre, j, 16);
      int sB = __shfl(pre, j + 1, 16);
      int sC = __shfl(pre, j + 2, 16);
      int sD = __shfl(pre, j + 3, 16);
      uint4 vA = Y4[(size_t)sA * 16 + lane];
      uint4 vB = Y4[(size_t)sB * 16 + lane];
      uint4 vC = Y4[(size_t)sC * 16 + lane];
      uint4 vD = Y4[(size_t)sD * 16 + lane];
      addbf8(sum, vA); addbf8(sum, vB); addbf8(sum, vC); addbf8(sum, vD);
    }
    for (; j < m; ++j) {
      int s = __shfl(pre, j, 16);
      addbf8(sum, Y4[(size_t)s * 16 + lane]);
    }
  }
  return 1.0f / fmaxf((float)(s1 - s0), 1.0f);
}

template<int NREL, int MODE>
__global__ __launch_bounds__(256) void gatherN_kernel(
    const unsigned short* __restrict__ Y0, const int* __restrict__ rp0, const int* __restrict__ sl0,
    const unsigned short* __restrict__ Y1, const int* __restrict__ rp1, const int* __restrict__ sl1,
    void* __restrict__ acc, int nnodes) {
  long g = (long)blockIdx.x * 256 + threadIdx.x;
  int node = (int)(g >> 4);
  if (node >= nnodes) return;
  int lane = (int)(g & 15);

  float t0[8] = {}, t1[8] = {};
  float inv0 = gather_one(reinterpret_cast<const uint4*>(Y0), rp0, sl0, node, lane, t0);
  float inv1 = 0.f;
  if (NREL == 2)
    inv1 = gather_one(reinterpret_cast<const uint4*>(Y1), rp1, sl1, node, lane, t1);

  if (MODE == 1) {  // bf16 permuted accumulator, elementwise
    unsigned short* ap = (unsigned short*)acc + (size_t)node * D + lane * 8;
    uint4 u = *reinterpret_cast<uint4*>(ap);
    float a[8];
    a[0] = __uint_as_float(u.x << 16); a[1] = __uint_as_float(u.x & 0xffff0000u);
    a[2] = __uint_as_float(u.y << 16); a[3] = __uint_as_float(u.y & 0xffff0000u);
    a[4] = __uint_as_float(u.z << 16); a[5] = __uint_as_float(u.z & 0xffff0000u);
    a[6] = __uint_as_float(u.w << 16); a[7] = __uint_as_float(u.w & 0xffff0000u);
#pragma unroll
    for (int i = 0; i < 8; ++i) {
      a[i] += t0[i] * inv0;
      if (NREL == 2) a[i] += t1[i] * inv1;
    }
    uint4 o;
    o.x = (unsigned)f2bf(a[0]) | ((unsigned)f2bf(a[1]) << 16);
    o.y = (unsigned)f2bf(a[2]) | ((unsigned)f2bf(a[3]) << 16);
    o.z = (unsigned)f2bf(a[4]) | ((unsigned)f2bf(a[5]) << 16);
    o.w = (unsigned)f2bf(a[6]) | ((unsigned)f2bf(a[7]) << 16);
    *reinterpret_cast<uint4*>(ap) = o;
  } else {  // f32 standard accumulator: position lane*8+i -> col i*16+lane
    float* ap = (float*)acc + (size_t)node * D + lane;
#pragma unroll
    for (int i = 0; i < 8; ++i) {
      float a = ap[i * 16];
      a += t0[i] * inv0;
      if (NREL == 2) a += t1[i] * inv1;
      ap[i * 16] = a;
    }
  }
}

// ---------------- launch ----------------

extern "C" void kernel_launch(void* const* d_in, const int* in_sizes, int n_in,
                              void* d_out, int out_size, void* d_ws, size_t ws_size,
                              hipStream_t stream) {
  const float* x_drug = (const float*)d_in[0];
  const float* x_prot = (const float*)d_in[1];
  const float* Wl0dp = (const float*)d_in[2];  const float* b0dp = (const float*)d_in[3];  const float* Wr0dp = (const float*)d_in[4];
  const float* Wl0pd = (const float*)d_in[5];  const float* b0pd = (const float*)d_in[6];  const float* Wr0pd = (const float*)d_in[7];
  const float* Wl0dd = (const float*)d_in[8];  const float* b0dd = (const float*)d_in[9];  const float* Wr0dd = (const float*)d_in[10];
  const float* Wl1dp = (const float*)d_in[11]; const float* b1dp = (const float*)d_in[12]; const float* Wr1dp = (const float*)d_in[13];
  const float* Wl1pd = (const float*)d_in[14]; const float* b1pd = (const float*)d_in[15]; const float* Wr1pd = (const float*)d_in[16];
  const float* Wl1dd = (const float*)d_in[17]; const float* b1dd = (const float*)d_in[18]; const float* Wr1dd = (const float*)d_in[19];
  const int* e_dp_s = (const int*)d_in[20]; const int* e_dp_d = (const int*)d_in[21];
  const int* e_pd_s = (const int*)d_in[22]; const int* e_pd_d = (const int*)d_in[23];
  const int* e_dd_s = (const int*)d_in[24]; const int* e_dd_d = (const int*)d_in[25];

  const int ND = in_sizes[0] / D;   // 200000
  const int NP = in_sizes[1] / D;   // 100000
  const int E_dp = in_sizes[20], E_pd = in_sizes[22], E_dd = in_sizes[24];

  // workspace layout (~218 MB, under proven 242)
  unsigned short* accD  = (unsigned short*)d_ws;              // ND*D bf16 (perm)
  unsigned short* accP  = accD + (size_t)ND * D;              // NP*D bf16 (perm)
  unsigned short* bufdd = accP + (size_t)NP * D;              // ND*D bf16 (perm)
  unsigned short* bufdp = bufdd + (size_t)ND * D;             // ND*D bf16 (perm)
  unsigned short* bufpd = bufdp + (size_t)ND * D;             // NP*D bf16 (perm)
  unsigned short* Wb    = bufpd + (size_t)NP * D;             // 5*D*D bf16 LDS image
  float* bsum  = (float*)(Wb + 5 * D * D);                    // D f32
  int* rp_dp  = (int*)(bsum + D);                             // NP+1
  int* rp_pd  = rp_dp + (NP + 2);                             // ND+1
  int* rp_dd  = rp_pd + (ND + 2);                             // ND+1
  int* sl_dp  = rp_dd + (ND + 2);                             // E_dp
  int* sl_pd  = sl_dp + E_dp;                                 // E_pd
  int* sl_dd  = sl_pd + E_pd;                                 // E_dd
  int* cnt    = sl_dd + E_dd;                                 // max(ND,NP)
  int* bsums  = cnt + ND;                                     // <=1024

  auto cdiv = [](long a, long b) { return (int)((a + b - 1) / b); };

  auto build_csr = [&](const int* esrc, const int* edst, int ne, int ndst,
                       int* rowptr, int* slots) {
    int nb = cdiv(ndst, 256);
    hipMemsetAsync(cnt, 0, (size_t)ndst * sizeof(int), stream);
    count_int_kernel<<<cdiv(ne, 256), 256, 0, stream>>>(edst, cnt, ne);
    blocksum_kernel<<<nb, 256, 0, stream>>>(cnt, bsums, ndst);
    scan_bsums_kernel<<<1, 256, 0, stream>>>(bsums, nb);
    scan_finalize_kernel<<<nb, 256, 0, stream>>>(cnt, bsums, rowptr, ndst, ne);
    hipMemcpyAsync(cnt, rowptr, (size_t)ndst * sizeof(int), hipMemcpyDeviceToDevice, stream);
    fill_kernel<<<cdiv(ne, 256), 256, 0, stream>>>(esrc, edst, cnt, slots, ne);
  };

  build_csr(e_dp_s, e_dp_d, E_dp, NP, rp_dp, sl_dp);
  build_csr(e_pd_s, e_pd_d, E_pd, ND, rp_pd, sl_pd);
  build_csr(e_dd_s, e_dd_d, E_dd, ND, rp_dd, sl_dd);

  const int tilesD = cdiv(ND, 256), tilesP = cdiv(NP, 256);

  // ---------- layer 0 (X = f32 standard, no relu-in; outputs bf16 permuted) ----------
  prep_weights_kernel<false><<<80, 256, 0, stream>>>(
      Wr0pd, Wr0dd, Wl0dd, Wl0dp, Wr0dp, Wl0pd, b0pd, b0dd, Wb, bsum);
  fused_gemm_kernel<float, false, 3, false><<<256, 512, 0, stream>>>(
      x_drug, Wb, bsum, accD, bufdd, bufdp, ND, tilesD);
  fused_gemm_kernel<float, false, 2, false><<<256, 512, 0, stream>>>(
      x_prot, Wb + 3 * D * D, b0dp, accP, bufpd, nullptr, NP, tilesP);
  gatherN_kernel<2, 1><<<cdiv((long)ND * 16, 256), 256, 0, stream>>>(
      bufpd, rp_pd, sl_pd, bufdd, rp_dd, sl_dd, accD, ND);
  gatherN_kernel<1, 1><<<cdiv((long)NP * 16, 256), 256, 0, stream>>>(
      bufdp, rp_dp, sl_dp, nullptr, nullptr, nullptr, accP, NP);

  // ---------- layer 1 (X = bf16 permuted + relu-in; head0 f32 standard to d_out) ----------
  float* outD1 = (float*)d_out;
  float* outP1 = outD1 + (size_t)ND * D;
  prep_weights_kernel<true><<<80, 256, 0, stream>>>(
      Wr1pd, Wr1dd, Wl1dd, Wl1dp, Wr1dp, Wl1pd, b1pd, b1dd, Wb, bsum);
  fused_gemm_kernel<unsigned short, true, 3, true><<<256, 512, 0, stream>>>(
      accD, Wb, bsum, outD1, bufdd, bufdp, ND, tilesD);
  fused_gemm_kernel<unsigned short, true, 2, true><<<256, 512, 0, stream>>>(
      accP, Wb + 3 * D * D, b1dp, outP1, bufpd, nullptr, NP, tilesP);
  gatherN_kernel<2, 0><<<cdiv((long)ND * 16, 256), 256, 0, stream>>>(
      bufpd, rp_pd, sl_pd, bufdd, rp_dd, sl_dd, outD1, ND);
  gatherN_kernel<1, 0><<<cdiv((long)NP * 16, 256), 256, 0, stream>>>(
      bufdp, rp_dp, sl_dp, nullptr, nullptr, nullptr, outP1, NP);
}

// Round 8
// 1069.075 us; speedup vs baseline: 1.0057x; 1.0057x over previous
//
#include <hip/hip_runtime.h>

#define D 128

using short8 = __attribute__((ext_vector_type(8))) short;
using f32x4 = __attribute__((ext_vector_type(4))) float;

__device__ inline unsigned short f2bf(float f) {
  unsigned u = __float_as_uint(f);
  u += 0x7fffu + ((u >> 16) & 1u);  // RNE
  return (unsigned short)(u >> 16);
}

// swizzled byte offset within a [128 rows][128 bf16] LDS/W-image tile (G4 fix)
__device__ inline int swz(int r, int kbyte) {
  return ((r << 8) + kbyte) ^ ((r & 7) << 4);
}

// relu on two packed bf16
__device__ inline unsigned relu_pk(unsigned w) {
  if (w & 0x8000u) w &= 0xffff0000u;
  if (w & 0x80000000u) w &= 0x0000ffffu;
  return w;
}

// ---------------- CSR build ----------------

__global__ __launch_bounds__(256) void count_int_kernel(const int* __restrict__ dst,
                                                        int* __restrict__ cnt, int n) {
  int i = blockIdx.x * 256 + threadIdx.x;
  if (i < n) atomicAdd(&cnt[dst[i]], 1);
}

__global__ __launch_bounds__(256) void blocksum_kernel(const int* __restrict__ cnt,
                                                       int* __restrict__ bsums, int n) {
  __shared__ int sh[256];
  int i = blockIdx.x * 256 + threadIdx.x;
  sh[threadIdx.x] = (i < n) ? cnt[i] : 0;
  __syncthreads();
#pragma unroll
  for (int off = 128; off > 0; off >>= 1) {
    if (threadIdx.x < off) sh[threadIdx.x] += sh[threadIdx.x + off];
    __syncthreads();
  }
  if (threadIdx.x == 0) bsums[blockIdx.x] = sh[0];
}

__global__ __launch_bounds__(256) void scan_bsums_kernel(int* __restrict__ bsums, int nb) {
  __shared__ int sh[256];
  __shared__ int carry;
  if (threadIdx.x == 0) carry = 0;
  __syncthreads();
  for (int base = 0; base < nb; base += 256) {
    int i = base + threadIdx.x;
    int v = (i < nb) ? bsums[i] : 0;
    sh[threadIdx.x] = v;
    __syncthreads();
#pragma unroll
    for (int off = 1; off < 256; off <<= 1) {
      int t = (threadIdx.x >= off) ? sh[threadIdx.x - off] : 0;
      __syncthreads();
      sh[threadIdx.x] += t;
      __syncthreads();
    }
    int incl = sh[threadIdx.x];
    if (i < nb) bsums[i] = carry + incl - v;  // exclusive
    __syncthreads();
    if (threadIdx.x == 0) carry += sh[255];
    __syncthreads();
  }
}

__global__ __launch_bounds__(256) void scan_finalize_kernel(const int* __restrict__ cnt,
                                                            const int* __restrict__ bsums,
                                                            int* __restrict__ rowptr,
                                                            int n, int total) {
  __shared__ int sh[256];
  int i = blockIdx.x * 256 + threadIdx.x;
  int v = (i < n) ? cnt[i] : 0;
  sh[threadIdx.x] = v;
  __syncthreads();
#pragma unroll
  for (int off = 1; off < 256; off <<= 1) {
    int t = (threadIdx.x >= off) ? sh[threadIdx.x - off] : 0;
    __syncthreads();
    sh[threadIdx.x] += t;
    __syncthreads();
  }
  if (i < n) {
    rowptr[i] = bsums[blockIdx.x] + sh[threadIdx.x] - v;
    if (i == n - 1) rowptr[n] = total;
  }
}

__global__ __launch_bounds__(256) void fill_kernel(const int* __restrict__ src,
                                                   const int* __restrict__ dst,
                                                   int* __restrict__ cursor,
                                                   int* __restrict__ slots, int n) {
  int i = blockIdx.x * 256 + threadIdx.x;
  if (i < n) {
    int pos = atomicAdd(&cursor[dst[i]], 1);
    slots[pos] = src[i];
  }
}

// ---------------- weight prep: write pre-swizzled LDS image (5 bf16 matrices) ----------------
// image layout per matrix: [c][k] tile, XOR-swizzled; PERM additionally permutes k
// so that k-position p corresponds to original col (p&7)*16 + (p>>3) — matching the
// permuted intermediate-buffer layout consumed as X by layer 1.
// Wb order: [0]=Wrpd+Wrdd (drug lin_r), [1]=Wldd, [2]=Wldp, [3]=Wrdp, [4]=Wlpd

template<bool PERM>
__global__ __launch_bounds__(256) void prep_weights_kernel(
    const float* __restrict__ Wrpd, const float* __restrict__ Wrdd,
    const float* __restrict__ Wldd, const float* __restrict__ Wldp,
    const float* __restrict__ Wrdp, const float* __restrict__ Wlpd,
    const float* __restrict__ bpd, const float* __restrict__ bdd,
    unsigned short* __restrict__ Wb, float* __restrict__ bsum) {
  int g = blockIdx.x * 256 + threadIdx.x;  // ushort4 granule id, 5*4096 total
  if (g < 5 * 4096) {
    int mat = g >> 12, idx = g & 4095;
    int c = idx >> 5, k4 = (idx & 31) * 4;  // k4 = first k-position of granule
    const float* src0;
    const float* src1 = nullptr;
    switch (mat) {
      case 0: src0 = Wrpd; src1 = Wrdd; break;
      case 1: src0 = Wldd; break;
      case 2: src0 = Wldp; break;
      case 3: src0 = Wrdp; break;
      default: src0 = Wlpd; break;
    }
    unsigned short v[4];
#pragma unroll
    for (int j = 0; j < 4; ++j) {
      int kp = k4 + j;
      int kc = PERM ? ((kp & 7) * 16 + (kp >> 3)) : kp;
      float f = src0[c * D + kc];
      if (src1) f += src1[c * D + kc];
      v[j] = f2bf(f);
    }
    *reinterpret_cast<ushort4*>((char*)(Wb + mat * D * D) + swz(c, k4 * 2)) =
        make_ushort4(v[0], v[1], v[2], v[3]);
  }
  if (g < D) bsum[g] = bpd[g] + bdd[g];
}

// ---------------- fragment loader ----------------

template<typename XT, bool RELU>
__device__ inline short8 ld_frag(const XT* __restrict__ p, bool valid) {
  if constexpr (sizeof(XT) == 4) {  // f32
    float4 v0 = make_float4(0.f, 0.f, 0.f, 0.f), v1 = v0;
    if (valid) {
      v0 = *reinterpret_cast<const float4*>(p);
      v1 = *reinterpret_cast<const float4*>(p + 4);
    }
    if (RELU) {
      v0.x = fmaxf(v0.x, 0.f); v0.y = fmaxf(v0.y, 0.f);
      v0.z = fmaxf(v0.z, 0.f); v0.w = fmaxf(v0.w, 0.f);
      v1.x = fmaxf(v1.x, 0.f); v1.y = fmaxf(v1.y, 0.f);
      v1.z = fmaxf(v1.z, 0.f); v1.w = fmaxf(v1.w, 0.f);
    }
    short8 s;
    s[0] = (short)f2bf(v0.x); s[1] = (short)f2bf(v0.y);
    s[2] = (short)f2bf(v0.z); s[3] = (short)f2bf(v0.w);
    s[4] = (short)f2bf(v1.x); s[5] = (short)f2bf(v1.y);
    s[6] = (short)f2bf(v1.z); s[7] = (short)f2bf(v1.w);
    return s;
  } else {  // bf16
    uint4 u = make_uint4(0, 0, 0, 0);
    if (valid) u = *reinterpret_cast<const uint4*>(p);
    if (RELU) { u.x = relu_pk(u.x); u.y = relu_pk(u.y); u.z = relu_pk(u.z); u.w = relu_pk(u.w); }
    union { uint4 u; short8 s; } cv; cv.u = u;
    return cv.s;
  }
}

// ---------------- fused multi-head GEMM (8 waves, 256-row macro-tile) ----------------
// head0: +bias; OUT0_F32 -> f32 standard-layout (d_out), else bf16 permuted-packed.
// heads 1..: bf16 permuted-packed (pos = (col&15)*8 + col>>4 -> one uint4 store per (m,r)).
// X prefetch double-buffered in registers; heads split into passes {0,1},{2} to cap VGPR.
// __launch_bounds__ arithmetic (VERIFIED rounds 6-7): HIP sets
// amdgpu-waves-per-eu = minB*maxT/64/4; VGPR cap = 512/waves_per_eu.
//   (512,2) -> 4 w/EU -> 128 cap -> spills (r6).  bare (512) -> same 128 (r7).
//   (512,1) -> 2 w/EU -> 256 cap -> live set ~220 fits, 2 waves/SIMD resident.

template<typename XT, bool RELU, int NH, bool OUT0_F32>
__global__ __launch_bounds__(512, 1) void fused_gemm_kernel(
    const XT* __restrict__ X, const unsigned short* __restrict__ Wb,
    const float* __restrict__ bias0, void* __restrict__ out0,
    unsigned short* __restrict__ out1, unsigned short* __restrict__ out2,
    int nrows, int ntiles) {
  __shared__ short Wsh[NH * D * D];
  const int tid = threadIdx.x;

  // Wb is the pre-swizzled LDS image: linear uint4 copy
  for (int i = tid; i < NH * 2048; i += 512)
    reinterpret_cast<uint4*>(Wsh)[i] = reinterpret_cast<const uint4*>(Wb)[i];
  __syncthreads();

  const int wv = tid >> 6, lane = tid & 63;
  const int l15 = lane & 15, lg = lane >> 4;
  const int rbase = wv * 32;

  float bias_c[8];
#pragma unroll
  for (int n = 0; n < 8; ++n) bias_c[n] = bias0[n * 16 + l15];

  auto loadA = [&](short8 (&a)[2][4], int tile) {
    size_t row0 = (size_t)tile * 256;
    long rem = (long)nrows - (long)row0;
    int limit = (int)(rem < 256 ? rem : 256);
    bool v0 = (rbase + l15) < limit, v1 = (rbase + l15 + 16) < limit;
    const XT* b0 = X + (row0 + rbase + l15) * D;
    const XT* b1 = X + (row0 + rbase + l15 + 16) * D;
#pragma unroll
    for (int t = 0; t < 4; ++t) {
      int k0 = t * 32 + lg * 8;
      a[0][t] = ld_frag<XT, RELU>(b0 + k0, v0);
      a[1][t] = ld_frag<XT, RELU>(b1 + k0, v1);
    }
  };

  // packed bf16 store (permuted layout): acc n-frags are lane-contiguous positions
  auto store_bf16 = [&](f32x4 (&acc)[2][8], unsigned short* out, size_t row0,
                        int limit, bool addb) {
#pragma unroll
    for (int m = 0; m < 2; ++m)
#pragma unroll
      for (int r = 0; r < 4; ++r) {
        int lrow = rbase + m * 16 + lg * 4 + r;
        if (lrow < limit) {
          float f[8];
#pragma unroll
          for (int n = 0; n < 8; ++n) f[n] = acc[m][n][r] + (addb ? bias_c[n] : 0.f);
          uint4 u;
          u.x = (unsigned)f2bf(f[0]) | ((unsigned)f2bf(f[1]) << 16);
          u.y = (unsigned)f2bf(f[2]) | ((unsigned)f2bf(f[3]) << 16);
          u.z = (unsigned)f2bf(f[4]) | ((unsigned)f2bf(f[5]) << 16);
          u.w = (unsigned)f2bf(f[6]) | ((unsigned)f2bf(f[7]) << 16);
          *reinterpret_cast<uint4*>(out + (row0 + lrow) * D + l15 * 8) = u;
        }
      }
  };

  auto store_f32 = [&](f32x4 (&acc)[2][8], float* out, size_t row0, int limit) {
#pragma unroll
    for (int m = 0; m < 2; ++m)
#pragma unroll
      for (int n = 0; n < 8; ++n) {
        const int col = n * 16 + l15;
#pragma unroll
        for (int r = 0; r < 4; ++r) {
          int lrow = rbase + m * 16 + lg * 4 + r;
          if (lrow < limit) out[(row0 + lrow) * D + col] = acc[m][n][r] + bias_c[n];
        }
      }
  };

  auto do_tile = [&](short8 (&acur)[2][4], short8 (&anext)[2][4], int tile) {
    int ntile = tile + (int)gridDim.x;
    if (ntile < ntiles) loadA(anext, ntile);  // prefetch hides under MFMA passes

    size_t row0 = (size_t)tile * 256;
    long rem = (long)nrows - (long)row0;
    int limit = (int)(rem < 256 ? rem : 256);

    // ---- pass 1: heads 0..P1-1 ----
    constexpr int P1 = (NH >= 2) ? 2 : 1;
    {
      f32x4 acc[P1][2][8] = {};
#pragma unroll
      for (int t = 0; t < 4; ++t) {
        const int kb = t * 64 + lg * 16;
#pragma unroll
        for (int h = 0; h < P1; ++h) {
          const char* base = (const char*)(Wsh + h * D * D);
#pragma unroll
          for (int n = 0; n < 8; ++n) {
            short8 b = *reinterpret_cast<const short8*>(base + swz(n * 16 + l15, kb));
            acc[h][0][n] = __builtin_amdgcn_mfma_f32_16x16x32_bf16(acur[0][t], b, acc[h][0][n], 0, 0, 0);
            acc[h][1][n] = __builtin_amdgcn_mfma_f32_16x16x32_bf16(acur[1][t], b, acc[h][1][n], 0, 0, 0);
          }
        }
      }
      if (OUT0_F32) store_f32(acc[0], (float*)out0, row0, limit);
      else          store_bf16(acc[0], (unsigned short*)out0, row0, limit, true);
      if (P1 > 1)   store_bf16(acc[1], out1, row0, limit, false);
    }
    // ---- pass 2: head 2 ----
    if constexpr (NH == 3) {
      f32x4 acc2[2][8] = {};
#pragma unroll
      for (int t = 0; t < 4; ++t) {
        const int kb = t * 64 + lg * 16;
        const char* base = (const char*)(Wsh + 2 * D * D);
#pragma unroll
        for (int n = 0; n < 8; ++n) {
          short8 b = *reinterpret_cast<const short8*>(base + swz(n * 16 + l15, kb));
          acc2[0][n] = __builtin_amdgcn_mfma_f32_16x16x32_bf16(acur[0][t], b, acc2[0][n], 0, 0, 0);
          acc2[1][n] = __builtin_amdgcn_mfma_f32_16x16x32_bf16(acur[1][t], b, acc2[1][n], 0, 0, 0);
        }
      }
      store_bf16(acc2, out2, row0, limit, false);
    }
  };

  short8 aA[2][4], aB[2][4];
  int tile = blockIdx.x;
  if (tile >= ntiles) return;
  loadA(aA, tile);
  while (true) {
    do_tile(aA, aB, tile);
    tile += gridDim.x;
    if (tile >= ntiles) break;
    do_tile(aB, aA, tile);
    tile += gridDim.x;
    if (tile >= ntiles) break;
  }
}

// ---------------- gather (CSR, no atomics) ----------------
// 16 lanes per dst node; lane owns 16B (8 bf16 positions) of the permuted 256B row.
// MODE 1: acc is bf16 permuted (elementwise uint4 RMW).
// MODE 0: acc is f32 standard layout -> un-permute: position lane*8+i == col i*16+lane.

__device__ inline void addbf8(float* sum, uint4 v) {
  sum[0] += __uint_as_float(v.x << 16);
  sum[1] += __uint_as_float(v.x & 0xffff0000u);
  sum[2] += __uint_as_float(v.y << 16);
  sum[3] += __uint_as_float(v.y & 0xffff0000u);
  sum[4] += __uint_as_float(v.z << 16);
  sum[5] += __uint_as_float(v.z & 0xffff0000u);
  sum[6] += __uint_as_float(v.w << 16);
  sum[7] += __uint_as_float(v.w & 0xffff0000u);
}

__device__ inline float gather_one(const uint4* __restrict__ Y4,
                                   const int* __restrict__ rowptr,
                                   const int* __restrict__ slots,
                                   int node, int lane, float* sum) {
  int s0 = rowptr[node], s1 = rowptr[node + 1];
  for (int chunk = s0; chunk < s1; chunk += 16) {
    int idx = chunk + lane;
    int pre = (idx < s1) ? slots[idx] : 0;
    int m = s1 - chunk; if (m > 16) m = 16;
    int j = 0;
    for (; j + 4 <= m; j += 4) {
      int sA = __shfl(pre, j, 16);
      int sB = __shfl(pre, j + 1, 16);
      int sC = __shfl(pre, j + 2, 16);
      int sD = __shfl(pre, j + 3, 16);
      uint4 vA = Y4[(size_t)sA * 16 + lane];
      uint4 vB = Y4[(size_t)sB * 16 + lane];
      uint4 vC = Y4[(size_t)sC * 16 + lane];
      uint4 vD = Y4[(size_t)sD * 16 + lane];
      addbf8(sum, vA); addbf8(sum, vB); addbf8(sum, vC); addbf8(sum, vD);
    }
    for (; j < m; ++j) {
      int s = __shfl(pre, j, 16);
      addbf8(sum, Y4[(size_t)s * 16 + lane]);
    }
  }
  return 1.0f / fmaxf((float)(s1 - s0), 1.0f);
}

template<int NREL, int MODE>
__global__ __launch_bounds__(256) void gatherN_kernel(
    const unsigned short* __restrict__ Y0, const int* __restrict__ rp0, const int* __restrict__ sl0,
    const unsigned short* __restrict__ Y1, const int* __restrict__ rp1, const int* __restrict__ sl1,
    void* __restrict__ acc, int nnodes) {
  long g = (long)blockIdx.x * 256 + threadIdx.x;
  int node = (int)(g >> 4);
  if (node >= nnodes) return;
  int lane = (int)(g & 15);

  float t0[8] = {}, t1[8] = {};
  float inv0 = gather_one(reinterpret_cast<const uint4*>(Y0), rp0, sl0, node, lane, t0);
  float inv1 = 0.f;
  if (NREL == 2)
    inv1 = gather_one(reinterpret_cast<const uint4*>(Y1), rp1, sl1, node, lane, t1);

  if (MODE == 1) {  // bf16 permuted accumulator, elementwise
    unsigned short* ap = (unsigned short*)acc + (size_t)node * D + lane * 8;
    uint4 u = *reinterpret_cast<uint4*>(ap);
    float a[8];
    a[0] = __uint_as_float(u.x << 16); a[1] = __uint_as_float(u.x & 0xffff0000u);
    a[2] = __uint_as_float(u.y << 16); a[3] = __uint_as_float(u.y & 0xffff0000u);
    a[4] = __uint_as_float(u.z << 16); a[5] = __uint_as_float(u.z & 0xffff0000u);
    a[6] = __uint_as_float(u.w << 16); a[7] = __uint_as_float(u.w & 0xffff0000u);
#pragma unroll
    for (int i = 0; i < 8; ++i) {
      a[i] += t0[i] * inv0;
      if (NREL == 2) a[i] += t1[i] * inv1;
    }
    uint4 o;
    o.x = (unsigned)f2bf(a[0]) | ((unsigned)f2bf(a[1]) << 16);
    o.y = (unsigned)f2bf(a[2]) | ((unsigned)f2bf(a[3]) << 16);
    o.z = (unsigned)f2bf(a[4]) | ((unsigned)f2bf(a[5]) << 16);
    o.w = (unsigned)f2bf(a[6]) | ((unsigned)f2bf(a[7]) << 16);
    *reinterpret_cast<uint4*>(ap) = o;
  } else {  // f32 standard accumulator: position lane*8+i -> col i*16+lane
    float* ap = (float*)acc + (size_t)node * D + lane;
#pragma unroll
    for (int i = 0; i < 8; ++i) {
      float a = ap[i * 16];
      a += t0[i] * inv0;
      if (NREL == 2) a += t1[i] * inv1;
      ap[i * 16] = a;
    }
  }
}

// ---------------- launch ----------------

extern "C" void kernel_launch(void* const* d_in, const int* in_sizes, int n_in,
                              void* d_out, int out_size, void* d_ws, size_t ws_size,
                              hipStream_t stream) {
  const float* x_drug = (const float*)d_in[0];
  const float* x_prot = (const float*)d_in[1];
  const float* Wl0dp = (const float*)d_in[2];  const float* b0dp = (const float*)d_in[3];  const float* Wr0dp = (const float*)d_in[4];
  const float* Wl0pd = (const float*)d_in[5];  const float* b0pd = (const float*)d_in[6];  const float* Wr0pd = (const float*)d_in[7];
  const float* Wl0dd = (const float*)d_in[8];  const float* b0dd = (const float*)d_in[9];  const float* Wr0dd = (const float*)d_in[10];
  const float* Wl1dp = (const float*)d_in[11]; const float* b1dp = (const float*)d_in[12]; const float* Wr1dp = (const float*)d_in[13];
  const float* Wl1pd = (const float*)d_in[14]; const float* b1pd = (const float*)d_in[15]; const float* Wr1pd = (const float*)d_in[16];
  const float* Wl1dd = (const float*)d_in[17]; const float* b1dd = (const float*)d_in[18]; const float* Wr1dd = (const float*)d_in[19];
  const int* e_dp_s = (const int*)d_in[20]; const int* e_dp_d = (const int*)d_in[21];
  const int* e_pd_s = (const int*)d_in[22]; const int* e_pd_d = (const int*)d_in[23];
  const int* e_dd_s = (const int*)d_in[24]; const int* e_dd_d = (const int*)d_in[25];

  const int ND = in_sizes[0] / D;   // 200000
  const int NP = in_sizes[1] / D;   // 100000
  const int E_dp = in_sizes[20], E_pd = in_sizes[22], E_dd = in_sizes[24];

  // workspace layout (~218 MB, under proven 242)
  unsigned short* accD  = (unsigned short*)d_ws;              // ND*D bf16 (perm)
  unsigned short* accP  = accD + (size_t)ND * D;              // NP*D bf16 (perm)
  unsigned short* bufdd = accP + (size_t)NP * D;              // ND*D bf16 (perm)
  unsigned short* bufdp = bufdd + (size_t)ND * D;             // ND*D bf16 (perm)
  unsigned short* bufpd = bufdp + (size_t)ND * D;             // NP*D bf16 (perm)
  unsigned short* Wb    = bufpd + (size_t)NP * D;             // 5*D*D bf16 LDS image
  float* bsum  = (float*)(Wb + 5 * D * D);                    // D f32
  int* rp_dp  = (int*)(bsum + D);                             // NP+1
  int* rp_pd  = rp_dp + (NP + 2);                             // ND+1
  int* rp_dd  = rp_pd + (ND + 2);                             // ND+1
  int* sl_dp  = rp_dd + (ND + 2);                             // E_dp
  int* sl_pd  = sl_dp + E_dp;                                 // E_pd
  int* sl_dd  = sl_pd + E_pd;                                 // E_dd
  int* cnt    = sl_dd + E_dd;                                 // max(ND,NP)
  int* bsums  = cnt + ND;                                     // <=1024

  auto cdiv = [](long a, long b) { return (int)((a + b - 1) / b); };

  auto build_csr = [&](const int* esrc, const int* edst, int ne, int ndst,
                       int* rowptr, int* slots) {
    int nb = cdiv(ndst, 256);
    hipMemsetAsync(cnt, 0, (size_t)ndst * sizeof(int), stream);
    count_int_kernel<<<cdiv(ne, 256), 256, 0, stream>>>(edst, cnt, ne);
    blocksum_kernel<<<nb, 256, 0, stream>>>(cnt, bsums, ndst);
    scan_bsums_kernel<<<1, 256, 0, stream>>>(bsums, nb);
    scan_finalize_kernel<<<nb, 256, 0, stream>>>(cnt, bsums, rowptr, ndst, ne);
    hipMemcpyAsync(cnt, rowptr, (size_t)ndst * sizeof(int), hipMemcpyDeviceToDevice, stream);
    fill_kernel<<<cdiv(ne, 256), 256, 0, stream>>>(esrc, edst, cnt, slots, ne);
  };

  build_csr(e_dp_s, e_dp_d, E_dp, NP, rp_dp, sl_dp);
  build_csr(e_pd_s, e_pd_d, E_pd, ND, rp_pd, sl_pd);
  build_csr(e_dd_s, e_dd_d, E_dd, ND, rp_dd, sl_dd);

  const int tilesD = cdiv(ND, 256), tilesP = cdiv(NP, 256);

  // ---------- layer 0 (X = f32 standard, no relu-in; outputs bf16 permuted) ----------
  prep_weights_kernel<false><<<80, 256, 0, stream>>>(
      Wr0pd, Wr0dd, Wl0dd, Wl0dp, Wr0dp, Wl0pd, b0pd, b0dd, Wb, bsum);
  fused_gemm_kernel<float, false, 3, false><<<256, 512, 0, stream>>>(
      x_drug, Wb, bsum, accD, bufdd, bufdp, ND, tilesD);
  fused_gemm_kernel<float, false, 2, false><<<256, 512, 0, stream>>>(
      x_prot, Wb + 3 * D * D, b0dp, accP, bufpd, nullptr, NP, tilesP);
  gatherN_kernel<2, 1><<<cdiv((long)ND * 16, 256), 256, 0, stream>>>(
      bufpd, rp_pd, sl_pd, bufdd, rp_dd, sl_dd, accD, ND);
  gatherN_kernel<1, 1><<<cdiv((long)NP * 16, 256), 256, 0, stream>>>(
      bufdp, rp_dp, sl_dp, nullptr, nullptr, nullptr, accP, NP);

  // ---------- layer 1 (X = bf16 permuted + relu-in; head0 f32 standard to d_out) ----------
  float* outD1 = (float*)d_out;
  float* outP1 = outD1 + (size_t)ND * D;
  prep_weights_kernel<true><<<80, 256, 0, stream>>>(
      Wr1pd, Wr1dd, Wl1dd, Wl1dp, Wr1dp, Wl1pd, b1pd, b1dd, Wb, bsum);
  fused_gemm_kernel<unsigned short, true, 3, true><<<256, 512, 0, stream>>>(
      accD, Wb, bsum, outD1, bufdd, bufdp, ND, tilesD);
  fused_gemm_kernel<unsigned short, true, 2, true><<<256, 512, 0, stream>>>(
      accP, Wb + 3 * D * D, b1dp, outP1, bufpd, nullptr, NP, tilesP);
  gatherN_kernel<2, 0><<<cdiv((long)ND * 16, 256), 256, 0, stream>>>(
      bufpd, rp_pd, sl_pd, bufdd, rp_dd, sl_dd, outD1, ND);
  gatherN_kernel<1, 0><<<cdiv((long)NP * 16, 256), 256, 0, stream>>>(
      bufdp, rp_dp, sl_dp, nullptr, nullptr, nullptr, outP1, NP);
}

// Round 9
// 898.806 us; speedup vs baseline: 1.1962x; 1.1894x over previous
//
#include <hip/hip_runtime.h>

#define D 128

using short8 = __attribute__((ext_vector_type(8))) short;
using f32x4 = __attribute__((ext_vector_type(4))) float;

__device__ inline unsigned short f2bf(float f) {
  unsigned u = __float_as_uint(f);
  u += 0x7fffu + ((u >> 16) & 1u);  // RNE
  return (unsigned short)(u >> 16);
}

// swizzled byte offset within a [128 rows][128 bf16] LDS/W-image tile (G4 fix)
__device__ inline int swz(int r, int kbyte) {
  return ((r << 8) + kbyte) ^ ((r & 7) << 4);
}

// relu on two packed bf16
__device__ inline unsigned relu_pk(unsigned w) {
  if (w & 0x8000u) w &= 0xffff0000u;
  if (w & 0x80000000u) w &= 0x0000ffffu;
  return w;
}

// ---------------- CSR build ----------------

__global__ __launch_bounds__(256) void count_int_kernel(const int* __restrict__ dst,
                                                        int* __restrict__ cnt, int n) {
  int i = blockIdx.x * 256 + threadIdx.x;
  if (i < n) atomicAdd(&cnt[dst[i]], 1);
}

__global__ __launch_bounds__(256) void blocksum_kernel(const int* __restrict__ cnt,
                                                       int* __restrict__ bsums, int n) {
  __shared__ int sh[256];
  int i = blockIdx.x * 256 + threadIdx.x;
  sh[threadIdx.x] = (i < n) ? cnt[i] : 0;
  __syncthreads();
#pragma unroll
  for (int off = 128; off > 0; off >>= 1) {
    if (threadIdx.x < off) sh[threadIdx.x] += sh[threadIdx.x + off];
    __syncthreads();
  }
  if (threadIdx.x == 0) bsums[blockIdx.x] = sh[0];
}

__global__ __launch_bounds__(256) void scan_bsums_kernel(int* __restrict__ bsums, int nb) {
  __shared__ int sh[256];
  __shared__ int carry;
  if (threadIdx.x == 0) carry = 0;
  __syncthreads();
  for (int base = 0; base < nb; base += 256) {
    int i = base + threadIdx.x;
    int v = (i < nb) ? bsums[i] : 0;
    sh[threadIdx.x] = v;
    __syncthreads();
#pragma unroll
    for (int off = 1; off < 256; off <<= 1) {
      int t = (threadIdx.x >= off) ? sh[threadIdx.x - off] : 0;
      __syncthreads();
      sh[threadIdx.x] += t;
      __syncthreads();
    }
    int incl = sh[threadIdx.x];
    if (i < nb) bsums[i] = carry + incl - v;  // exclusive
    __syncthreads();
    if (threadIdx.x == 0) carry += sh[255];
    __syncthreads();
  }
}

__global__ __launch_bounds__(256) void scan_finalize_kernel(const int* __restrict__ cnt,
                                                            const int* __restrict__ bsums,
                                                            int* __restrict__ rowptr,
                                                            int n, int total) {
  __shared__ int sh[256];
  int i = blockIdx.x * 256 + threadIdx.x;
  int v = (i < n) ? cnt[i] : 0;
  sh[threadIdx.x] = v;
  __syncthreads();
#pragma unroll
  for (int off = 1; off < 256; off <<= 1) {
    int t = (threadIdx.x >= off) ? sh[threadIdx.x - off] : 0;
    __syncthreads();
    sh[threadIdx.x] += t;
    __syncthreads();
  }
  if (i < n) {
    rowptr[i] = bsums[blockIdx.x] + sh[threadIdx.x] - v;
    if (i == n - 1) rowptr[n] = total;
  }
}

__global__ __launch_bounds__(256) void fill_kernel(const int* __restrict__ src,
                                                   const int* __restrict__ dst,
                                                   int* __restrict__ cursor,
                                                   int* __restrict__ slots, int n) {
  int i = blockIdx.x * 256 + threadIdx.x;
  if (i < n) {
    int pos = atomicAdd(&cursor[dst[i]], 1);
    slots[pos] = src[i];
  }
}

// ---------------- weight prep: write pre-swizzled LDS image (5 bf16 matrices) ----------------
// image layout per matrix: [c][k] tile, XOR-swizzled; PERM additionally permutes k
// so that k-position p corresponds to original col (p&7)*16 + (p>>3) — matching the
// permuted intermediate-buffer layout consumed as X by layer 1.
// Wb order: [0]=Wrpd+Wrdd (drug lin_r), [1]=Wldd, [2]=Wldp, [3]=Wrdp, [4]=Wlpd

template<bool PERM>
__global__ __launch_bounds__(256) void prep_weights_kernel(
    const float* __restrict__ Wrpd, const float* __restrict__ Wrdd,
    const float* __restrict__ Wldd, const float* __restrict__ Wldp,
    const float* __restrict__ Wrdp, const float* __restrict__ Wlpd,
    const float* __restrict__ bpd, const float* __restrict__ bdd,
    unsigned short* __restrict__ Wb, float* __restrict__ bsum) {
  int g = blockIdx.x * 256 + threadIdx.x;  // ushort4 granule id, 5*4096 total
  if (g < 5 * 4096) {
    int mat = g >> 12, idx = g & 4095;
    int c = idx >> 5, k4 = (idx & 31) * 4;  // k4 = first k-position of granule
    const float* src0;
    const float* src1 = nullptr;
    switch (mat) {
      case 0: src0 = Wrpd; src1 = Wrdd; break;
      case 1: src0 = Wldd; break;
      case 2: src0 = Wldp; break;
      case 3: src0 = Wrdp; break;
      default: src0 = Wlpd; break;
    }
    unsigned short v[4];
#pragma unroll
    for (int j = 0; j < 4; ++j) {
      int kp = k4 + j;
      int kc = PERM ? ((kp & 7) * 16 + (kp >> 3)) : kp;
      float f = src0[c * D + kc];
      if (src1) f += src1[c * D + kc];
      v[j] = f2bf(f);
    }
    *reinterpret_cast<ushort4*>((char*)(Wb + mat * D * D) + swz(c, k4 * 2)) =
        make_ushort4(v[0], v[1], v[2], v[3]);
  }
  if (g < D) bsum[g] = bpd[g] + bdd[g];
}

// ---------------- fragment loader ----------------

template<typename XT, bool RELU>
__device__ inline short8 ld_frag(const XT* __restrict__ p, bool valid) {
  if constexpr (sizeof(XT) == 4) {  // f32
    float4 v0 = make_float4(0.f, 0.f, 0.f, 0.f), v1 = v0;
    if (valid) {
      v0 = *reinterpret_cast<const float4*>(p);
      v1 = *reinterpret_cast<const float4*>(p + 4);
    }
    if (RELU) {
      v0.x = fmaxf(v0.x, 0.f); v0.y = fmaxf(v0.y, 0.f);
      v0.z = fmaxf(v0.z, 0.f); v0.w = fmaxf(v0.w, 0.f);
      v1.x = fmaxf(v1.x, 0.f); v1.y = fmaxf(v1.y, 0.f);
      v1.z = fmaxf(v1.z, 0.f); v1.w = fmaxf(v1.w, 0.f);
    }
    short8 s;
    s[0] = (short)f2bf(v0.x); s[1] = (short)f2bf(v0.y);
    s[2] = (short)f2bf(v0.z); s[3] = (short)f2bf(v0.w);
    s[4] = (short)f2bf(v1.x); s[5] = (short)f2bf(v1.y);
    s[6] = (short)f2bf(v1.z); s[7] = (short)f2bf(v1.w);
    return s;
  } else {  // bf16
    uint4 u = make_uint4(0, 0, 0, 0);
    if (valid) u = *reinterpret_cast<const uint4*>(p);
    if (RELU) { u.x = relu_pk(u.x); u.y = relu_pk(u.y); u.z = relu_pk(u.z); u.w = relu_pk(u.w); }
    union { uint4 u; short8 s; } cv; cv.u = u;
    return cv.s;
  }
}

// ---------------- fused multi-head GEMM (4 waves, 128-row macro-tile) ----------------
// head0: +bias; OUT0_F32 -> f32 standard-layout (d_out), else bf16 permuted-packed.
// heads 1..: bf16 permuted-packed (pos = (col&15)*8 + col>>4 -> one uint4 store per (m,r)).
// X prefetch double-buffered in registers; heads split into passes {0,1},{2} to cap VGPR.
// 256-thread blocks: rounds 6-8 proved 512-thread blocks get a hard 128-VGPR cap
// (spills, hbm 3.4x); round 5 proved 256-thread blocks are granted ~228 VGPR, no spill.

template<typename XT, bool RELU, int NH, bool OUT0_F32>
__global__ __launch_bounds__(256, 1) void fused_gemm_kernel(
    const XT* __restrict__ X, const unsigned short* __restrict__ Wb,
    const float* __restrict__ bias0, void* __restrict__ out0,
    unsigned short* __restrict__ out1, unsigned short* __restrict__ out2,
    int nrows, int ntiles) {
  __shared__ short Wsh[NH * D * D];
  const int tid = threadIdx.x;

  // Wb is the pre-swizzled LDS image: linear uint4 copy
  for (int i = tid; i < NH * 2048; i += 256)
    reinterpret_cast<uint4*>(Wsh)[i] = reinterpret_cast<const uint4*>(Wb)[i];
  __syncthreads();

  const int wv = tid >> 6, lane = tid & 63;
  const int l15 = lane & 15, lg = lane >> 4;
  const int rbase = wv * 32;

  float bias_c[8];
#pragma unroll
  for (int n = 0; n < 8; ++n) bias_c[n] = bias0[n * 16 + l15];

  auto loadA = [&](short8 (&a)[2][4], int tile) {
    size_t row0 = (size_t)tile * 128;
    long rem = (long)nrows - (long)row0;
    int limit = (int)(rem < 128 ? rem : 128);
    bool v0 = (rbase + l15) < limit, v1 = (rbase + l15 + 16) < limit;
    const XT* b0 = X + (row0 + rbase + l15) * D;
    const XT* b1 = X + (row0 + rbase + l15 + 16) * D;
#pragma unroll
    for (int t = 0; t < 4; ++t) {
      int k0 = t * 32 + lg * 8;
      a[0][t] = ld_frag<XT, RELU>(b0 + k0, v0);
      a[1][t] = ld_frag<XT, RELU>(b1 + k0, v1);
    }
  };

  // packed bf16 store (permuted layout): acc n-frags are lane-contiguous positions
  auto store_bf16 = [&](f32x4 (&acc)[2][8], unsigned short* out, size_t row0,
                        int limit, bool addb) {
#pragma unroll
    for (int m = 0; m < 2; ++m)
#pragma unroll
      for (int r = 0; r < 4; ++r) {
        int lrow = rbase + m * 16 + lg * 4 + r;
        if (lrow < limit) {
          float f[8];
#pragma unroll
          for (int n = 0; n < 8; ++n) f[n] = acc[m][n][r] + (addb ? bias_c[n] : 0.f);
          uint4 u;
          u.x = (unsigned)f2bf(f[0]) | ((unsigned)f2bf(f[1]) << 16);
          u.y = (unsigned)f2bf(f[2]) | ((unsigned)f2bf(f[3]) << 16);
          u.z = (unsigned)f2bf(f[4]) | ((unsigned)f2bf(f[5]) << 16);
          u.w = (unsigned)f2bf(f[6]) | ((unsigned)f2bf(f[7]) << 16);
          *reinterpret_cast<uint4*>(out + (row0 + lrow) * D + l15 * 8) = u;
        }
      }
  };

  auto store_f32 = [&](f32x4 (&acc)[2][8], float* out, size_t row0, int limit) {
#pragma unroll
    for (int m = 0; m < 2; ++m)
#pragma unroll
      for (int n = 0; n < 8; ++n) {
        const int col = n * 16 + l15;
#pragma unroll
        for (int r = 0; r < 4; ++r) {
          int lrow = rbase + m * 16 + lg * 4 + r;
          if (lrow < limit) out[(row0 + lrow) * D + col] = acc[m][n][r] + bias_c[n];
        }
      }
  };

  auto do_tile = [&](short8 (&acur)[2][4], short8 (&anext)[2][4], int tile) {
    int ntile = tile + (int)gridDim.x;
    if (ntile < ntiles) loadA(anext, ntile);  // prefetch hides under MFMA passes

    size_t row0 = (size_t)tile * 128;
    long rem = (long)nrows - (long)row0;
    int limit = (int)(rem < 128 ? rem : 128);

    // ---- pass 1: heads 0..P1-1 ----
    constexpr int P1 = (NH >= 2) ? 2 : 1;
    {
      f32x4 acc[P1][2][8] = {};
#pragma unroll
      for (int t = 0; t < 4; ++t) {
        const int kb = t * 64 + lg * 16;
#pragma unroll
        for (int h = 0; h < P1; ++h) {
          const char* base = (const char*)(Wsh + h * D * D);
#pragma unroll
          for (int n = 0; n < 8; ++n) {
            short8 b = *reinterpret_cast<const short8*>(base + swz(n * 16 + l15, kb));
            acc[h][0][n] = __builtin_amdgcn_mfma_f32_16x16x32_bf16(acur[0][t], b, acc[h][0][n], 0, 0, 0);
            acc[h][1][n] = __builtin_amdgcn_mfma_f32_16x16x32_bf16(acur[1][t], b, acc[h][1][n], 0, 0, 0);
          }
        }
      }
      if (OUT0_F32) store_f32(acc[0], (float*)out0, row0, limit);
      else          store_bf16(acc[0], (unsigned short*)out0, row0, limit, true);
      if (P1 > 1)   store_bf16(acc[1], out1, row0, limit, false);
    }
    // ---- pass 2: head 2 ----
    if constexpr (NH == 3) {
      f32x4 acc2[2][8] = {};
#pragma unroll
      for (int t = 0; t < 4; ++t) {
        const int kb = t * 64 + lg * 16;
        const char* base = (const char*)(Wsh + 2 * D * D);
#pragma unroll
        for (int n = 0; n < 8; ++n) {
          short8 b = *reinterpret_cast<const short8*>(base + swz(n * 16 + l15, kb));
          acc2[0][n] = __builtin_amdgcn_mfma_f32_16x16x32_bf16(acur[0][t], b, acc2[0][n], 0, 0, 0);
          acc2[1][n] = __builtin_amdgcn_mfma_f32_16x16x32_bf16(acur[1][t], b, acc2[1][n], 0, 0, 0);
        }
      }
      store_bf16(acc2, out2, row0, limit, false);
    }
  };

  short8 aA[2][4], aB[2][4];
  int tile = blockIdx.x;
  if (tile >= ntiles) return;
  loadA(aA, tile);
  while (true) {
    do_tile(aA, aB, tile);
    tile += gridDim.x;
    if (tile >= ntiles) break;
    do_tile(aB, aA, tile);
    tile += gridDim.x;
    if (tile >= ntiles) break;
  }
}

// ---------------- gather (CSR, no atomics) ----------------
// 16 lanes per dst node; lane owns 16B (8 bf16 positions) of the permuted 256B row.
// MODE 1: acc is bf16 permuted (elementwise uint4 RMW).
// MODE 0: acc is f32 standard layout -> un-permute: position lane*8+i == col i*16+lane.

__device__ inline void addbf8(float* sum, uint4 v) {
  sum[0] += __uint_as_float(v.x << 16);
  sum[1] += __uint_as_float(v.x & 0xffff0000u);
  sum[2] += __uint_as_float(v.y << 16);
  sum[3] += __uint_as_float(v.y & 0xffff0000u);
  sum[4] += __uint_as_float(v.z << 16);
  sum[5] += __uint_as_float(v.z & 0xffff0000u);
  sum[6] += __uint_as_float(v.w << 16);
  sum[7] += __uint_as_float(v.w & 0xffff0000u);
}

__device__ inline float gather_one(const uint4* __restrict__ Y4,
                                   const int* __restrict__ rowptr,
                                   const int* __restrict__ slots,
                                   int node, int lane, float* sum) {
  int s0 = rowptr[node], s1 = rowptr[node + 1];
  for (int chunk = s0; chunk < s1; chunk += 16) {
    int idx = chunk + lane;
    int pre = (idx < s1) ? slots[idx] : 0;
    int m = s1 - chunk; if (m > 16) m = 16;
    int j = 0;
    for (; j + 4 <= m; j += 4) {
      int sA = __shfl(pre, j, 16);
      int sB = __shfl(pre, j + 1, 16);
      int sC = __shfl(pre, j + 2, 16);
      int sD = __shfl(pre, j + 3, 16);
      uint4 vA = Y4[(size_t)sA * 16 + lane];
      uint4 vB = Y4[(size_t)sB * 16 + lane];
      uint4 vC = Y4[(size_t)sC * 16 + lane];
      uint4 vD = Y4[(size_t)sD * 16 + lane];
      addbf8(sum, vA); addbf8(sum, vB); addbf8(sum, vC); addbf8(sum, vD);
    }
    for (; j < m; ++j) {
      int s = __shfl(pre, j, 16);
      addbf8(sum, Y4[(size_t)s * 16 + lane]);
    }
  }
  return 1.0f / fmaxf((float)(s1 - s0), 1.0f);
}

template<int NREL, int MODE>
__global__ __launch_bounds__(256) void gatherN_kernel(
    const unsigned short* __restrict__ Y0, const int* __restrict__ rp0, const int* __restrict__ sl0,
    const unsigned short* __restrict__ Y1, const int* __restrict__ rp1, const int* __restrict__ sl1,
    void* __restrict__ acc, int nnodes) {
  long g = (long)blockIdx.x * 256 + threadIdx.x;
  int node = (int)(g >> 4);
  if (node >= nnodes) return;
  int lane = (int)(g & 15);

  float t0[8] = {}, t1[8] = {};
  float inv0 = gather_one(reinterpret_cast<const uint4*>(Y0), rp0, sl0, node, lane, t0);
  float inv1 = 0.f;
  if (NREL == 2)
    inv1 = gather_one(reinterpret_cast<const uint4*>(Y1), rp1, sl1, node, lane, t1);

  if (MODE == 1) {  // bf16 permuted accumulator, elementwise
    unsigned short* ap = (unsigned short*)acc + (size_t)node * D + lane * 8;
    uint4 u = *reinterpret_cast<uint4*>(ap);
    float a[8];
    a[0] = __uint_as_float(u.x << 16); a[1] = __uint_as_float(u.x & 0xffff0000u);
    a[2] = __uint_as_float(u.y << 16); a[3] = __uint_as_float(u.y & 0xffff0000u);
    a[4] = __uint_as_float(u.z << 16); a[5] = __uint_as_float(u.z & 0xffff0000u);
    a[6] = __uint_as_float(u.w << 16); a[7] = __uint_as_float(u.w & 0xffff0000u);
#pragma unroll
    for (int i = 0; i < 8; ++i) {
      a[i] += t0[i] * inv0;
      if (NREL == 2) a[i] += t1[i] * inv1;
    }
    uint4 o;
    o.x = (unsigned)f2bf(a[0]) | ((unsigned)f2bf(a[1]) << 16);
    o.y = (unsigned)f2bf(a[2]) | ((unsigned)f2bf(a[3]) << 16);
    o.z = (unsigned)f2bf(a[4]) | ((unsigned)f2bf(a[5]) << 16);
    o.w = (unsigned)f2bf(a[6]) | ((unsigned)f2bf(a[7]) << 16);
    *reinterpret_cast<uint4*>(ap) = o;
  } else {  // f32 standard accumulator: position lane*8+i -> col i*16+lane
    float* ap = (float*)acc + (size_t)node * D + lane;
#pragma unroll
    for (int i = 0; i < 8; ++i) {
      float a = ap[i * 16];
      a += t0[i] * inv0;
      if (NREL == 2) a += t1[i] * inv1;
      ap[i * 16] = a;
    }
  }
}

// ---------------- launch ----------------

extern "C" void kernel_launch(void* const* d_in, const int* in_sizes, int n_in,
                              void* d_out, int out_size, void* d_ws, size_t ws_size,
                              hipStream_t stream) {
  const float* x_drug = (const float*)d_in[0];
  const float* x_prot = (const float*)d_in[1];
  const float* Wl0dp = (const float*)d_in[2];  const float* b0dp = (const float*)d_in[3];  const float* Wr0dp = (const float*)d_in[4];
  const float* Wl0pd = (const float*)d_in[5];  const float* b0pd = (const float*)d_in[6];  const float* Wr0pd = (const float*)d_in[7];
  const float* Wl0dd = (const float*)d_in[8];  const float* b0dd = (const float*)d_in[9];  const float* Wr0dd = (const float*)d_in[10];
  const float* Wl1dp = (const float*)d_in[11]; const float* b1dp = (const float*)d_in[12]; const float* Wr1dp = (const float*)d_in[13];
  const float* Wl1pd = (const float*)d_in[14]; const float* b1pd = (const float*)d_in[15]; const float* Wr1pd = (const float*)d_in[16];
  const float* Wl1dd = (const float*)d_in[17]; const float* b1dd = (const float*)d_in[18]; const float* Wr1dd = (const float*)d_in[19];
  const int* e_dp_s = (const int*)d_in[20]; const int* e_dp_d = (const int*)d_in[21];
  const int* e_pd_s = (const int*)d_in[22]; const int* e_pd_d = (const int*)d_in[23];
  const int* e_dd_s = (const int*)d_in[24]; const int* e_dd_d = (const int*)d_in[25];

  const int ND = in_sizes[0] / D;   // 200000
  const int NP = in_sizes[1] / D;   // 100000
  const int E_dp = in_sizes[20], E_pd = in_sizes[22], E_dd = in_sizes[24];

  // workspace layout (~218 MB, under proven 242)
  unsigned short* accD  = (unsigned short*)d_ws;              // ND*D bf16 (perm)
  unsigned short* accP  = accD + (size_t)ND * D;              // NP*D bf16 (perm)
  unsigned short* bufdd = accP + (size_t)NP * D;              // ND*D bf16 (perm)
  unsigned short* bufdp = bufdd + (size_t)ND * D;             // ND*D bf16 (perm)
  unsigned short* bufpd = bufdp + (size_t)ND * D;             // NP*D bf16 (perm)
  unsigned short* Wb    = bufpd + (size_t)NP * D;             // 5*D*D bf16 LDS image
  float* bsum  = (float*)(Wb + 5 * D * D);                    // D f32
  int* rp_dp  = (int*)(bsum + D);                             // NP+1
  int* rp_pd  = rp_dp + (NP + 2);                             // ND+1
  int* rp_dd  = rp_pd + (ND + 2);                             // ND+1
  int* sl_dp  = rp_dd + (ND + 2);                             // E_dp
  int* sl_pd  = sl_dp + E_dp;                                 // E_pd
  int* sl_dd  = sl_pd + E_pd;                                 // E_dd
  int* cnt    = sl_dd + E_dd;                                 // max(ND,NP)
  int* bsums  = cnt + ND;                                     // <=1024

  auto cdiv = [](long a, long b) { return (int)((a + b - 1) / b); };

  auto build_csr = [&](const int* esrc, const int* edst, int ne, int ndst,
                       int* rowptr, int* slots) {
    int nb = cdiv(ndst, 256);
    hipMemsetAsync(cnt, 0, (size_t)ndst * sizeof(int), stream);
    count_int_kernel<<<cdiv(ne, 256), 256, 0, stream>>>(edst, cnt, ne);
    blocksum_kernel<<<nb, 256, 0, stream>>>(cnt, bsums, ndst);
    scan_bsums_kernel<<<1, 256, 0, stream>>>(bsums, nb);
    scan_finalize_kernel<<<nb, 256, 0, stream>>>(cnt, bsums, rowptr, ndst, ne);
    hipMemcpyAsync(cnt, rowptr, (size_t)ndst * sizeof(int), hipMemcpyDeviceToDevice, stream);
    fill_kernel<<<cdiv(ne, 256), 256, 0, stream>>>(esrc, edst, cnt, slots, ne);
  };

  build_csr(e_dp_s, e_dp_d, E_dp, NP, rp_dp, sl_dp);
  build_csr(e_pd_s, e_pd_d, E_pd, ND, rp_pd, sl_pd);
  build_csr(e_dd_s, e_dd_d, E_dd, ND, rp_dd, sl_dd);

  const int tilesD = cdiv(ND, 128), tilesP = cdiv(NP, 128);

  // ---------- layer 0 (X = f32 standard, no relu-in; outputs bf16 permuted) ----------
  prep_weights_kernel<false><<<80, 256, 0, stream>>>(
      Wr0pd, Wr0dd, Wl0dd, Wl0dp, Wr0dp, Wl0pd, b0pd, b0dd, Wb, bsum);
  fused_gemm_kernel<float, false, 3, false><<<256, 256, 0, stream>>>(
      x_drug, Wb, bsum, accD, bufdd, bufdp, ND, tilesD);
  fused_gemm_kernel<float, false, 2, false><<<512, 256, 0, stream>>>(
      x_prot, Wb + 3 * D * D, b0dp, accP, bufpd, nullptr, NP, tilesP);
  gatherN_kernel<2, 1><<<cdiv((long)ND * 16, 256), 256, 0, stream>>>(
      bufpd, rp_pd, sl_pd, bufdd, rp_dd, sl_dd, accD, ND);
  gatherN_kernel<1, 1><<<cdiv((long)NP * 16, 256), 256, 0, stream>>>(
      bufdp, rp_dp, sl_dp, nullptr, nullptr, nullptr, accP, NP);

  // ---------- layer 1 (X = bf16 permuted + relu-in; head0 f32 standard to d_out) ----------
  float* outD1 = (float*)d_out;
  float* outP1 = outD1 + (size_t)ND * D;
  prep_weights_kernel<true><<<80, 256, 0, stream>>>(
      Wr1pd, Wr1dd, Wl1dd, Wl1dp, Wr1dp, Wl1pd, b1pd, b1dd, Wb, bsum);
  fused_gemm_kernel<unsigned short, true, 3, true><<<256, 256, 0, stream>>>(
      accD, Wb, bsum, outD1, bufdd, bufdp, ND, tilesD);
  fused_gemm_kernel<unsigned short, true, 2, true><<<512, 256, 0, stream>>>(
      accP, Wb + 3 * D * D, b1dp, outP1, bufpd, nullptr, NP, tilesP);
  gatherN_kernel<2, 0><<<cdiv((long)ND * 16, 256), 256, 0, stream>>>(
      bufpd, rp_pd, sl_pd, bufdd, rp_dd, sl_dd, outD1, ND);
  gatherN_kernel<1, 0><<<cdiv((long)NP * 16, 256), 256, 0, stream>>>(
      bufdp, rp_dp, sl_dp, nullptr, nullptr, nullptr, outP1, NP);
}

// Round 10
// 819.795 us; speedup vs baseline: 1.3115x; 1.0964x over previous
//
#include <hip/hip_runtime.h>

#define D 128

using short8 = __attribute__((ext_vector_type(8))) short;
using f32x4 = __attribute__((ext_vector_type(4))) float;

__device__ inline unsigned short f2bf(float f) {
  unsigned u = __float_as_uint(f);
  u += 0x7fffu + ((u >> 16) & 1u);  // RNE
  return (unsigned short)(u >> 16);
}

// swizzled byte offset within a [128 rows][128 bf16] LDS/W-image tile (G4 fix)
__device__ inline int swz(int r, int kbyte) {
  return ((r << 8) + kbyte) ^ ((r & 7) << 4);
}

// relu on two packed bf16
__device__ inline unsigned relu_pk(unsigned w) {
  if (w & 0x8000u) w &= 0xffff0000u;
  if (w & 0x80000000u) w &= 0x0000ffffu;
  return w;
}

// ---------------- CSR build ----------------

__global__ __launch_bounds__(256) void count_int_kernel(const int* __restrict__ dst,
                                                        int* __restrict__ cnt, int n) {
  int i = blockIdx.x * 256 + threadIdx.x;
  if (i < n) atomicAdd(&cnt[dst[i]], 1);
}

__global__ __launch_bounds__(256) void blocksum_kernel(const int* __restrict__ cnt,
                                                       int* __restrict__ bsums, int n) {
  __shared__ int sh[256];
  int i = blockIdx.x * 256 + threadIdx.x;
  sh[threadIdx.x] = (i < n) ? cnt[i] : 0;
  __syncthreads();
#pragma unroll
  for (int off = 128; off > 0; off >>= 1) {
    if (threadIdx.x < off) sh[threadIdx.x] += sh[threadIdx.x + off];
    __syncthreads();
  }
  if (threadIdx.x == 0) bsums[blockIdx.x] = sh[0];
}

__global__ __launch_bounds__(256) void scan_bsums_kernel(int* __restrict__ bsums, int nb) {
  __shared__ int sh[256];
  __shared__ int carry;
  if (threadIdx.x == 0) carry = 0;
  __syncthreads();
  for (int base = 0; base < nb; base += 256) {
    int i = base + threadIdx.x;
    int v = (i < nb) ? bsums[i] : 0;
    sh[threadIdx.x] = v;
    __syncthreads();
#pragma unroll
    for (int off = 1; off < 256; off <<= 1) {
      int t = (threadIdx.x >= off) ? sh[threadIdx.x - off] : 0;
      __syncthreads();
      sh[threadIdx.x] += t;
      __syncthreads();
    }
    int incl = sh[threadIdx.x];
    if (i < nb) bsums[i] = carry + incl - v;  // exclusive
    __syncthreads();
    if (threadIdx.x == 0) carry += sh[255];
    __syncthreads();
  }
}

__global__ __launch_bounds__(256) void scan_finalize_kernel(const int* __restrict__ cnt,
                                                            const int* __restrict__ bsums,
                                                            int* __restrict__ rowptr,
                                                            int n, int total) {
  __shared__ int sh[256];
  int i = blockIdx.x * 256 + threadIdx.x;
  int v = (i < n) ? cnt[i] : 0;
  sh[threadIdx.x] = v;
  __syncthreads();
#pragma unroll
  for (int off = 1; off < 256; off <<= 1) {
    int t = (threadIdx.x >= off) ? sh[threadIdx.x - off] : 0;
    __syncthreads();
    sh[threadIdx.x] += t;
    __syncthreads();
  }
  if (i < n) {
    rowptr[i] = bsums[blockIdx.x] + sh[threadIdx.x] - v;
    if (i == n - 1) rowptr[n] = total;
  }
}

__global__ __launch_bounds__(256) void fill_kernel(const int* __restrict__ src,
                                                   const int* __restrict__ dst,
                                                   int* __restrict__ cursor,
                                                   int* __restrict__ slots, int n) {
  int i = blockIdx.x * 256 + threadIdx.x;
  if (i < n) {
    int pos = atomicAdd(&cursor[dst[i]], 1);
    slots[pos] = src[i];
  }
}

// ---------------- weight prep: write pre-swizzled LDS image (5 bf16 matrices) ----------------
// Wb order: [0]=Wrpd+Wrdd (drug lin_r), [1]=Wldd, [2]=Wldp, [3]=Wrdp, [4]=Wlpd

template<bool PERM>
__global__ __launch_bounds__(256) void prep_weights_kernel(
    const float* __restrict__ Wrpd, const float* __restrict__ Wrdd,
    const float* __restrict__ Wldd, const float* __restrict__ Wldp,
    const float* __restrict__ Wrdp, const float* __restrict__ Wlpd,
    const float* __restrict__ bpd, const float* __restrict__ bdd,
    unsigned short* __restrict__ Wb, float* __restrict__ bsum) {
  int g = blockIdx.x * 256 + threadIdx.x;  // ushort4 granule id, 5*4096 total
  if (g < 5 * 4096) {
    int mat = g >> 12, idx = g & 4095;
    int c = idx >> 5, k4 = (idx & 31) * 4;
    const float* src0;
    const float* src1 = nullptr;
    switch (mat) {
      case 0: src0 = Wrpd; src1 = Wrdd; break;
      case 1: src0 = Wldd; break;
      case 2: src0 = Wldp; break;
      case 3: src0 = Wrdp; break;
      default: src0 = Wlpd; break;
    }
    unsigned short v[4];
#pragma unroll
    for (int j = 0; j < 4; ++j) {
      int kp = k4 + j;
      int kc = PERM ? ((kp & 7) * 16 + (kp >> 3)) : kp;
      float f = src0[c * D + kc];
      if (src1) f += src1[c * D + kc];
      v[j] = f2bf(f);
    }
    *reinterpret_cast<ushort4*>((char*)(Wb + mat * D * D) + swz(c, k4 * 2)) =
        make_ushort4(v[0], v[1], v[2], v[3]);
  }
  if (g < D) bsum[g] = bpd[g] + bdd[g];
}

// ---------------- fragment loader ----------------

template<typename XT, bool RELU>
__device__ inline short8 ld_frag(const XT* __restrict__ p, bool valid) {
  if constexpr (sizeof(XT) == 4) {  // f32
    float4 v0 = make_float4(0.f, 0.f, 0.f, 0.f), v1 = v0;
    if (valid) {
      v0 = *reinterpret_cast<const float4*>(p);
      v1 = *reinterpret_cast<const float4*>(p + 4);
    }
    if (RELU) {
      v0.x = fmaxf(v0.x, 0.f); v0.y = fmaxf(v0.y, 0.f);
      v0.z = fmaxf(v0.z, 0.f); v0.w = fmaxf(v0.w, 0.f);
      v1.x = fmaxf(v1.x, 0.f); v1.y = fmaxf(v1.y, 0.f);
      v1.z = fmaxf(v1.z, 0.f); v1.w = fmaxf(v1.w, 0.f);
    }
    short8 s;
    s[0] = (short)f2bf(v0.x); s[1] = (short)f2bf(v0.y);
    s[2] = (short)f2bf(v0.z); s[3] = (short)f2bf(v0.w);
    s[4] = (short)f2bf(v1.x); s[5] = (short)f2bf(v1.y);
    s[6] = (short)f2bf(v1.z); s[7] = (short)f2bf(v1.w);
    return s;
  } else {  // bf16
    uint4 u = make_uint4(0, 0, 0, 0);
    if (valid) u = *reinterpret_cast<const uint4*>(p);
    if (RELU) { u.x = relu_pk(u.x); u.y = relu_pk(u.y); u.z = relu_pk(u.z); u.w = relu_pk(u.w); }
    union { uint4 u; short8 s; } cv; cv.u = u;
    return cv.s;
  }
}

// ---------------- fused multi-head GEMM (4 waves, 128-row macro-tile) ----------------
// SEQUENTIAL single-head passes (acc = 64 VGPR/pass; round 9 showed dual-head acc
// hits the 256-VGPR cap and spills ~110 MB). Drug work split across TWO kernels
// (NH=2: 64 KB LDS + NH=1: 32 KB LDS) so 2 blocks/CU fit -> 2 waves/SIMD.
// head0: +bias (bias0 nullable -> zeros); OUT0_F32 -> f32 standard layout, else
// bf16 permuted-packed (pos=(col&15)*8+col>>4 -> one uint4 store per (m,r)).

template<typename XT, bool RELU, int NH, bool OUT0_F32>
__global__ __launch_bounds__(256, 1) void fused_gemm_kernel(
    const XT* __restrict__ X, const unsigned short* __restrict__ Wb,
    const float* __restrict__ bias0, void* __restrict__ out0,
    unsigned short* __restrict__ out1,
    int nrows, int ntiles) {
  __shared__ short Wsh[NH * D * D];
  const int tid = threadIdx.x;

  // Wb is the pre-swizzled LDS image: linear uint4 copy
  for (int i = tid; i < NH * 2048; i += 256)
    reinterpret_cast<uint4*>(Wsh)[i] = reinterpret_cast<const uint4*>(Wb)[i];
  __syncthreads();

  const int wv = tid >> 6, lane = tid & 63;
  const int l15 = lane & 15, lg = lane >> 4;
  const int rbase = wv * 32;

  float bias_c[8];
#pragma unroll
  for (int n = 0; n < 8; ++n) bias_c[n] = bias0 ? bias0[n * 16 + l15] : 0.f;

  auto loadA = [&](short8 (&a)[2][4], int tile) {
    size_t row0 = (size_t)tile * 128;
    long rem = (long)nrows - (long)row0;
    int limit = (int)(rem < 128 ? rem : 128);
    bool v0 = (rbase + l15) < limit, v1 = (rbase + l15 + 16) < limit;
    const XT* b0 = X + (row0 + rbase + l15) * D;
    const XT* b1 = X + (row0 + rbase + l15 + 16) * D;
#pragma unroll
    for (int t = 0; t < 4; ++t) {
      int k0 = t * 32 + lg * 8;
      a[0][t] = ld_frag<XT, RELU>(b0 + k0, v0);
      a[1][t] = ld_frag<XT, RELU>(b1 + k0, v1);
    }
  };

  // packed bf16 store (permuted layout)
  auto store_bf16 = [&](f32x4 (&acc)[2][8], unsigned short* out, size_t row0,
                        int limit, bool addb) {
#pragma unroll
    for (int m = 0; m < 2; ++m)
#pragma unroll
      for (int r = 0; r < 4; ++r) {
        int lrow = rbase + m * 16 + lg * 4 + r;
        if (lrow < limit) {
          float f[8];
#pragma unroll
          for (int n = 0; n < 8; ++n) f[n] = acc[m][n][r] + (addb ? bias_c[n] : 0.f);
          uint4 u;
          u.x = (unsigned)f2bf(f[0]) | ((unsigned)f2bf(f[1]) << 16);
          u.y = (unsigned)f2bf(f[2]) | ((unsigned)f2bf(f[3]) << 16);
          u.z = (unsigned)f2bf(f[4]) | ((unsigned)f2bf(f[5]) << 16);
          u.w = (unsigned)f2bf(f[6]) | ((unsigned)f2bf(f[7]) << 16);
          *reinterpret_cast<uint4*>(out + (row0 + lrow) * D + l15 * 8) = u;
        }
      }
  };

  auto store_f32 = [&](f32x4 (&acc)[2][8], float* out, size_t row0, int limit) {
#pragma unroll
    for (int m = 0; m < 2; ++m)
#pragma unroll
      for (int n = 0; n < 8; ++n) {
        const int col = n * 16 + l15;
#pragma unroll
        for (int r = 0; r < 4; ++r) {
          int lrow = rbase + m * 16 + lg * 4 + r;
          if (lrow < limit) out[(row0 + lrow) * D + col] = acc[m][n][r] + bias_c[n];
        }
      }
  };

  auto do_tile = [&](short8 (&acur)[2][4], short8 (&anext)[2][4], int tile) {
    int ntile = tile + (int)gridDim.x;
    if (ntile < ntiles) loadA(anext, ntile);  // prefetch hides under MFMA passes

    size_t row0 = (size_t)tile * 128;
    long rem = (long)nrows - (long)row0;
    int limit = (int)(rem < 128 ? rem : 128);

#pragma unroll
    for (int h = 0; h < NH; ++h) {
      f32x4 acc[2][8] = {};
#pragma unroll
      for (int t = 0; t < 4; ++t) {
        const int kb = t * 64 + lg * 16;
        const char* base = (const char*)(Wsh + h * D * D);
#pragma unroll
        for (int n = 0; n < 8; ++n) {
          short8 b = *reinterpret_cast<const short8*>(base + swz(n * 16 + l15, kb));
          acc[0][n] = __builtin_amdgcn_mfma_f32_16x16x32_bf16(acur[0][t], b, acc[0][n], 0, 0, 0);
          acc[1][n] = __builtin_amdgcn_mfma_f32_16x16x32_bf16(acur[1][t], b, acc[1][n], 0, 0, 0);
        }
      }
      if (h == 0) {
        if (OUT0_F32) store_f32(acc, (float*)out0, row0, limit);
        else          store_bf16(acc, (unsigned short*)out0, row0, limit, true);
      } else {
        store_bf16(acc, out1, row0, limit, false);
      }
    }
  };

  short8 aA[2][4], aB[2][4];
  int tile = blockIdx.x;
  if (tile >= ntiles) return;
  loadA(aA, tile);
  while (true) {
    do_tile(aA, aB, tile);
    tile += gridDim.x;
    if (tile >= ntiles) break;
    do_tile(aB, aA, tile);
    tile += gridDim.x;
    if (tile >= ntiles) break;
  }
}

// ---------------- gather (CSR, no atomics) ----------------
// 16 lanes per dst node; lane owns 16B (8 bf16 positions) of the permuted 256B row.
// MODE 1: acc is bf16 permuted (elementwise uint4 RMW).
// MODE 0: acc is f32 standard layout -> un-permute: position lane*8+i == col i*16+lane.

__device__ inline void addbf8(float* sum, uint4 v) {
  sum[0] += __uint_as_float(v.x << 16);
  sum[1] += __uint_as_float(v.x & 0xffff0000u);
  sum[2] += __uint_as_float(v.y << 16);
  sum[3] += __uint_as_float(v.y & 0xffff0000u);
  sum[4] += __uint_as_float(v.z << 16);
  sum[5] += __uint_as_float(v.z & 0xffff0000u);
  sum[6] += __uint_as_float(v.w << 16);
  sum[7] += __uint_as_float(v.w & 0xffff0000u);
}

__device__ inline float gather_one(const uint4* __restrict__ Y4,
                                   const int* __restrict__ rowptr,
                                   const int* __restrict__ slots,
                                   int node, int lane, float* sum) {
  int s0 = rowptr[node], s1 = rowptr[node + 1];
  for (int chunk = s0; chunk < s1; chunk += 16) {
    int idx = chunk + lane;
    int pre = (idx < s1) ? slots[idx] : 0;
    int m = s1 - chunk; if (m > 16) m = 16;
    int j = 0;
    for (; j + 4 <= m; j += 4) {
      int sA = __shfl(pre, j, 16);
      int sB = __shfl(pre, j + 1, 16);
      int sC = __shfl(pre, j + 2, 16);
      int sD = __shfl(pre, j + 3, 16);
      uint4 vA = Y4[(size_t)sA * 16 + lane];
      uint4 vB = Y4[(size_t)sB * 16 + lane];
      uint4 vC = Y4[(size_t)sC * 16 + lane];
      uint4 vD = Y4[(size_t)sD * 16 + lane];
      addbf8(sum, vA); addbf8(sum, vB); addbf8(sum, vC); addbf8(sum, vD);
    }
    for (; j < m; ++j) {
      int s = __shfl(pre, j, 16);
      addbf8(sum, Y4[(size_t)s * 16 + lane]);
    }
  }
  return 1.0f / fmaxf((float)(s1 - s0), 1.0f);
}

template<int NREL, int MODE>
__global__ __launch_bounds__(256) void gatherN_kernel(
    const unsigned short* __restrict__ Y0, const int* __restrict__ rp0, const int* __restrict__ sl0,
    const unsigned short* __restrict__ Y1, const int* __restrict__ rp1, const int* __restrict__ sl1,
    void* __restrict__ acc, int nnodes) {
  long g = (long)blockIdx.x * 256 + threadIdx.x;
  int node = (int)(g >> 4);
  if (node >= nnodes) return;
  int lane = (int)(g & 15);

  float t0[8] = {}, t1[8] = {};
  float inv0 = gather_one(reinterpret_cast<const uint4*>(Y0), rp0, sl0, node, lane, t0);
  float inv1 = 0.f;
  if (NREL == 2)
    inv1 = gather_one(reinterpret_cast<const uint4*>(Y1), rp1, sl1, node, lane, t1);

  if (MODE == 1) {  // bf16 permuted accumulator, elementwise
    unsigned short* ap = (unsigned short*)acc + (size_t)node * D + lane * 8;
    uint4 u = *reinterpret_cast<uint4*>(ap);
    float a[8];
    a[0] = __uint_as_float(u.x << 16); a[1] = __uint_as_float(u.x & 0xffff0000u);
    a[2] = __uint_as_float(u.y << 16); a[3] = __uint_as_float(u.y & 0xffff0000u);
    a[4] = __uint_as_float(u.z << 16); a[5] = __uint_as_float(u.z & 0xffff0000u);
    a[6] = __uint_as_float(u.w << 16); a[7] = __uint_as_float(u.w & 0xffff0000u);
#pragma unroll
    for (int i = 0; i < 8; ++i) {
      a[i] += t0[i] * inv0;
      if (NREL == 2) a[i] += t1[i] * inv1;
    }
    uint4 o;
    o.x = (unsigned)f2bf(a[0]) | ((unsigned)f2bf(a[1]) << 16);
    o.y = (unsigned)f2bf(a[2]) | ((unsigned)f2bf(a[3]) << 16);
    o.z = (unsigned)f2bf(a[4]) | ((unsigned)f2bf(a[5]) << 16);
    o.w = (unsigned)f2bf(a[6]) | ((unsigned)f2bf(a[7]) << 16);
    *reinterpret_cast<uint4*>(ap) = o;
  } else {  // f32 standard accumulator: position lane*8+i -> col i*16+lane
    float* ap = (float*)acc + (size_t)node * D + lane;
#pragma unroll
    for (int i = 0; i < 8; ++i) {
      float a = ap[i * 16];
      a += t0[i] * inv0;
      if (NREL == 2) a += t1[i] * inv1;
      ap[i * 16] = a;
    }
  }
}

// ---------------- launch ----------------

extern "C" void kernel_launch(void* const* d_in, const int* in_sizes, int n_in,
                              void* d_out, int out_size, void* d_ws, size_t ws_size,
                              hipStream_t stream) {
  const float* x_drug = (const float*)d_in[0];
  const float* x_prot = (const float*)d_in[1];
  const float* Wl0dp = (const float*)d_in[2];  const float* b0dp = (const float*)d_in[3];  const float* Wr0dp = (const float*)d_in[4];
  const float* Wl0pd = (const float*)d_in[5];  const float* b0pd = (const float*)d_in[6];  const float* Wr0pd = (const float*)d_in[7];
  const float* Wl0dd = (const float*)d_in[8];  const float* b0dd = (const float*)d_in[9];  const float* Wr0dd = (const float*)d_in[10];
  const float* Wl1dp = (const float*)d_in[11]; const float* b1dp = (const float*)d_in[12]; const float* Wr1dp = (const float*)d_in[13];
  const float* Wl1pd = (const float*)d_in[14]; const float* b1pd = (const float*)d_in[15]; const float* Wr1pd = (const float*)d_in[16];
  const float* Wl1dd = (const float*)d_in[17]; const float* b1dd = (const float*)d_in[18]; const float* Wr1dd = (const float*)d_in[19];
  const int* e_dp_s = (const int*)d_in[20]; const int* e_dp_d = (const int*)d_in[21];
  const int* e_pd_s = (const int*)d_in[22]; const int* e_pd_d = (const int*)d_in[23];
  const int* e_dd_s = (const int*)d_in[24]; const int* e_dd_d = (const int*)d_in[25];

  const int ND = in_sizes[0] / D;   // 200000
  const int NP = in_sizes[1] / D;   // 100000
  const int E_dp = in_sizes[20], E_pd = in_sizes[22], E_dd = in_sizes[24];

  // workspace layout (~218 MB, under proven 242)
  unsigned short* accD  = (unsigned short*)d_ws;              // ND*D bf16 (perm)
  unsigned short* accP  = accD + (size_t)ND * D;              // NP*D bf16 (perm)
  unsigned short* bufdd = accP + (size_t)NP * D;              // ND*D bf16 (perm)
  unsigned short* bufdp = bufdd + (size_t)ND * D;             // ND*D bf16 (perm)
  unsigned short* bufpd = bufdp + (size_t)ND * D;             // NP*D bf16 (perm)
  unsigned short* Wb    = bufpd + (size_t)NP * D;             // 5*D*D bf16 LDS image
  float* bsum  = (float*)(Wb + 5 * D * D);                    // D f32
  int* rp_dp  = (int*)(bsum + D);                             // NP+1
  int* rp_pd  = rp_dp + (NP + 2);                             // ND+1
  int* rp_dd  = rp_pd + (ND + 2);                             // ND+1
  int* sl_dp  = rp_dd + (ND + 2);                             // E_dp
  int* sl_pd  = sl_dp + E_dp;                                 // E_pd
  int* sl_dd  = sl_pd + E_pd;                                 // E_dd
  int* cnt    = sl_dd + E_dd;                                 // max(ND,NP)
  int* bsums  = cnt + ND;                                     // <=1024

  auto cdiv = [](long a, long b) { return (int)((a + b - 1) / b); };

  auto build_csr = [&](const int* esrc, const int* edst, int ne, int ndst,
                       int* rowptr, int* slots) {
    int nb = cdiv(ndst, 256);
    hipMemsetAsync(cnt, 0, (size_t)ndst * sizeof(int), stream);
    count_int_kernel<<<cdiv(ne, 256), 256, 0, stream>>>(edst, cnt, ne);
    blocksum_kernel<<<nb, 256, 0, stream>>>(cnt, bsums, ndst);
    scan_bsums_kernel<<<1, 256, 0, stream>>>(bsums, nb);
    scan_finalize_kernel<<<nb, 256, 0, stream>>>(cnt, bsums, rowptr, ndst, ne);
    hipMemcpyAsync(cnt, rowptr, (size_t)ndst * sizeof(int), hipMemcpyDeviceToDevice, stream);
    fill_kernel<<<cdiv(ne, 256), 256, 0, stream>>>(esrc, edst, cnt, slots, ne);
  };

  build_csr(e_dp_s, e_dp_d, E_dp, NP, rp_dp, sl_dp);
  build_csr(e_pd_s, e_pd_d, E_pd, ND, rp_pd, sl_pd);
  build_csr(e_dd_s, e_dd_d, E_dd, ND, rp_dd, sl_dd);

  const int tilesD = cdiv(ND, 128), tilesP = cdiv(NP, 128);

  // ---------- layer 0 (X = f32 standard, no relu-in; outputs bf16 permuted) ----------
  prep_weights_kernel<false><<<80, 256, 0, stream>>>(
      Wr0pd, Wr0dd, Wl0dd, Wl0dp, Wr0dp, Wl0pd, b0pd, b0dd, Wb, bsum);
  // drug: heads {lin_r(+bsum), Wldd} then {Wldp}
  fused_gemm_kernel<float, false, 2, false><<<512, 256, 0, stream>>>(
      x_drug, Wb, bsum, accD, bufdd, ND, tilesD);
  fused_gemm_kernel<float, false, 1, false><<<512, 256, 0, stream>>>(
      x_drug, Wb + 2 * D * D, nullptr, bufdp, nullptr, ND, tilesD);
  // protein: heads {Wrdp(+b_dp), Wlpd}
  fused_gemm_kernel<float, false, 2, false><<<512, 256, 0, stream>>>(
      x_prot, Wb + 3 * D * D, b0dp, accP, bufpd, NP, tilesP);
  gatherN_kernel<2, 1><<<cdiv((long)ND * 16, 256), 256, 0, stream>>>(
      bufpd, rp_pd, sl_pd, bufdd, rp_dd, sl_dd, accD, ND);
  gatherN_kernel<1, 1><<<cdiv((long)NP * 16, 256), 256, 0, stream>>>(
      bufdp, rp_dp, sl_dp, nullptr, nullptr, nullptr, accP, NP);

  // ---------- layer 1 (X = bf16 permuted + relu-in; head0 f32 standard to d_out) ----------
  float* outD1 = (float*)d_out;
  float* outP1 = outD1 + (size_t)ND * D;
  prep_weights_kernel<true><<<80, 256, 0, stream>>>(
      Wr1pd, Wr1dd, Wl1dd, Wl1dp, Wr1dp, Wl1pd, b1pd, b1dd, Wb, bsum);
  fused_gemm_kernel<unsigned short, true, 2, true><<<512, 256, 0, stream>>>(
      accD, Wb, bsum, outD1, bufdd, ND, tilesD);
  fused_gemm_kernel<unsigned short, true, 1, false><<<512, 256, 0, stream>>>(
      accD, Wb + 2 * D * D, nullptr, bufdp, nullptr, ND, tilesD);
  fused_gemm_kernel<unsigned short, true, 2, true><<<512, 256, 0, stream>>>(
      accP, Wb + 3 * D * D, b1dp, outP1, bufpd, NP, tilesP);
  gatherN_kernel<2, 0><<<cdiv((long)ND * 16, 256), 256, 0, stream>>>(
      bufpd, rp_pd, sl_pd, bufdd, rp_dd, sl_dd, outD1, ND);
  gatherN_kernel<1, 0><<<cdiv((long)NP * 16, 256), 256, 0, stream>>>(
      bufdp, rp_dp, sl_dp, nullptr, nullptr, nullptr, outP1, NP);
}